// Round 5
// baseline (577.573 us; speedup 1.0000x reference)
//
#include <hip/hip_runtime.h>
#include <hip/hip_bf16.h>

// DKVMN fused pipeline for MI355X (gfx950)
// B=256, T=512, DIM_KEY=256, DIM_VALUE=128, NUM_ITEM=2000
// k0_cvt : f32 tables -> bf16 tables in ws
// k1_wea : gather + [Mk|e_W|a_W] GEMM (bf16 MFMA) + softmax/sigmoid/tanh -> ws
// k2_scan: per-batch scan; M state in VGPRs, 8 waves split v; CHUNK-level
//          double-buffered loads (whole next 8-step chunk issued at chunk
//          start -> barrier vmcnt drain is free); chunked deferred reduce
// k3_f   : [reads|k] @ f_W^T GEMM (bf16 MFMA) + tanh -> ws (aliases e)
// k4_pred: sigmoid(f . p_W + p_b) -> d_out (f32)

#define T_SEQ 512
#define DK    256
#define DV    128
#define NITEM 2000
#define BT    131072   // 256*512

typedef __attribute__((ext_vector_type(8))) short bf16x8;
typedef __attribute__((ext_vector_type(4))) float f32x4;
typedef __attribute__((ext_vector_type(2))) float f32x2;

__device__ __forceinline__ float bf2f(unsigned short u) {
    return __uint_as_float(((unsigned int)u) << 16);
}
__device__ __forceinline__ unsigned short f2bf(float x) {   // RNE f32->bf16
    unsigned int u = __float_as_uint(x);
    return (unsigned short)((u + 0x7fffu + ((u >> 16) & 1u)) >> 16);
}
__device__ __forceinline__ float fast_rcp(float x) { return __builtin_amdgcn_rcpf(x); }
__device__ __forceinline__ float fast_sigmoid(float x) { return fast_rcp(1.f + __expf(-x)); }
__device__ __forceinline__ float fast_tanh(float x) {
    float t = __expf(2.f * x);
    return (t - 1.f) * fast_rcp(t + 1.f);
}

// 2xf32 fma helper. NOTE (R2 post-mortem): v_pk_fma_f32 is throughput-neutral
// on CDNA4 (157.3 TF peak == scalar fma rate); this exists only for brevity.
__device__ __forceinline__ f32x2 pk_fma(f32x2 a, f32x2 b, f32x2 c) {
#if __has_builtin(__builtin_elementwise_fma)
    return __builtin_elementwise_fma(a, b, c);
#else
    f32x2 d; d.x = fmaf(a.x, b.x, c.x); d.y = fmaf(a.y, b.y, c.y); return d;
#endif
}

// ---------------------------------------------------------------------------
// k0: f32 -> bf16 table conversion (up to 5 tables per launch, y = table id)
// ---------------------------------------------------------------------------
__global__ __launch_bounds__(256) void k0_cvt(
    const float* __restrict__ s0, const float* __restrict__ s1,
    const float* __restrict__ s2, const float* __restrict__ s3,
    const float* __restrict__ s4,
    unsigned short* __restrict__ d0, unsigned short* __restrict__ d1,
    unsigned short* __restrict__ d2, unsigned short* __restrict__ d3,
    unsigned short* __restrict__ d4,
    int n0, int n1, int n2, int n3, int n4)
{
    const float* s; unsigned short* d; int n;
    switch (blockIdx.y) {
        case 0:  s = s0; d = d0; n = n0; break;
        case 1:  s = s1; d = d1; n = n1; break;
        case 2:  s = s2; d = d2; n = n2; break;
        case 3:  s = s3; d = d3; n = n3; break;
        default: s = s4; d = d4; n = n4; break;
    }
    int i4 = (blockIdx.x * 256 + threadIdx.x) * 4;
    if (i4 < n) {
        float4 v = *(const float4*)(s + i4);
        ushort4 o;
        o.x = f2bf(v.x); o.y = f2bf(v.y); o.z = f2bf(v.z); o.w = f2bf(v.w);
        *(ushort4*)(d + i4) = o;
    }
}

// ---------------------------------------------------------------------------
// K1: 128 rows x 128 cols per block, 4 waves stacked by rows.
// ---------------------------------------------------------------------------
__global__ __launch_bounds__(256) void k1_wea(
    const int* __restrict__ item_seq, const int* __restrict__ correct_seq,
    const unsigned short* __restrict__ k_bf, const unsigned short* __restrict__ v_bf,
    const unsigned short* __restrict__ Mk_bf,
    const unsigned short* __restrict__ eW_bf, const float* __restrict__ e_b,
    const unsigned short* __restrict__ aW_bf, const float* __restrict__ a_b,
    unsigned short* __restrict__ Wout, unsigned short* __restrict__ Eout,
    unsigned short* __restrict__ Aout)
{
    const int m_tile = blockIdx.x;   // 0..1023
    const int n_tile = blockIdx.y;   // 0..4
    const int tid  = threadIdx.x;
    const int lane = tid & 63;
    const int wv   = tid >> 6;

    __shared__ int idx_s[128];
    __shared__ unsigned short A_s[128 * 40];
    __shared__ unsigned short B_s[128 * 40];

    const unsigned short* Atab = (n_tile == 0) ? k_bf : v_bf;
    const unsigned short* Wtab; int wrow0;
    if (n_tile == 0)      { Wtab = Mk_bf; wrow0 = 0;   }
    else if (n_tile == 1) { Wtab = eW_bf; wrow0 = 0;   }
    else if (n_tile == 2) { Wtab = eW_bf; wrow0 = 128; }
    else if (n_tile == 3) { Wtab = aW_bf; wrow0 = 0;   }
    else                  { Wtab = aW_bf; wrow0 = 128; }

    if (tid < 128) {
        int pos = m_tile * 128 + tid;
        int it = item_seq[pos];
        int co = correct_seq[pos];
        idx_s[tid] = (n_tile == 0) ? it : (it + NITEM * co);
    }
    __syncthreads();

    int myrow[4], myc4[4], myidx[4];
    #pragma unroll
    for (int j = 0; j < 4; ++j) {
        int chunk = tid + 256 * j;
        myrow[j] = chunk >> 3;
        myc4[j]  = chunk & 7;
        myidx[j] = idx_s[myrow[j]];
    }

    f32x4 acc[2][8];
    #pragma unroll
    for (int mi = 0; mi < 2; ++mi)
        #pragma unroll
        for (int ni = 0; ni < 8; ++ni)
            acc[mi][ni] = (f32x4){0.f, 0.f, 0.f, 0.f};

    for (int bk = 0; bk < 8; ++bk) {
        int k0 = bk * 32;
        #pragma unroll
        for (int j = 0; j < 4; ++j) {
            int row = myrow[j], c4 = myc4[j];
            *(ushort4*)&A_s[row * 40 + c4 * 4] =
                *(const ushort4*)(Atab + (long)myidx[j] * DK + k0 + c4 * 4);
            *(ushort4*)&B_s[row * 40 + c4 * 4] =
                *(const ushort4*)(Wtab + (long)(wrow0 + row) * DK + k0 + c4 * 4);
        }
        __syncthreads();

        const int kq = lane >> 4;   // k-slot 0..3 (8 bf16 each)
        const int rr = lane & 15;
        bf16x8 af[2], bfr[8];
        #pragma unroll
        for (int mi = 0; mi < 2; ++mi)
            af[mi] = *(const bf16x8*)&A_s[(wv * 32 + mi * 16 + rr) * 40 + kq * 8];
        #pragma unroll
        for (int ni = 0; ni < 8; ++ni)
            bfr[ni] = *(const bf16x8*)&B_s[(ni * 16 + rr) * 40 + kq * 8];
        #pragma unroll
        for (int ni = 0; ni < 8; ++ni)
            #pragma unroll
            for (int mi = 0; mi < 2; ++mi)
                acc[mi][ni] = __builtin_amdgcn_mfma_f32_16x16x32_bf16(
                    af[mi], bfr[ni], acc[mi][ni], 0, 0, 0);
        __syncthreads();
    }

    // C/D layout: col = lane&15, row = (lane>>4)*4 + reg (m89-verified)
    const int rowbase = m_tile * 128 + wv * 32;
    const int cgrp = lane >> 4;
    const int cc   = lane & 15;

    if (n_tile == 0) {
        #pragma unroll
        for (int mi = 0; mi < 2; ++mi) {
            #pragma unroll
            for (int i = 0; i < 4; ++i) {
                float m = -1e30f;
                #pragma unroll
                for (int ni = 0; ni < 8; ++ni) m = fmaxf(m, acc[mi][ni][i]);
                m = fmaxf(m, __shfl_xor(m, 1));
                m = fmaxf(m, __shfl_xor(m, 2));
                m = fmaxf(m, __shfl_xor(m, 4));
                m = fmaxf(m, __shfl_xor(m, 8));
                float p[8]; float s = 0.f;
                #pragma unroll
                for (int ni = 0; ni < 8; ++ni) { p[ni] = __expf(acc[mi][ni][i] - m); s += p[ni]; }
                s += __shfl_xor(s, 1); s += __shfl_xor(s, 2);
                s += __shfl_xor(s, 4); s += __shfl_xor(s, 8);
                float inv = fast_rcp(s);
                int row = rowbase + mi * 16 + cgrp * 4 + i;
                #pragma unroll
                for (int ni = 0; ni < 8; ++ni)
                    Wout[(long)row * 128 + ni * 16 + cc] = f2bf(p[ni] * inv);
            }
        }
    } else {
        const bool is_e = (n_tile <= 2);
        const float* bias = is_e ? e_b : a_b;
        const int colbase = (is_e ? (n_tile - 1) : (n_tile - 3)) * 128;
        unsigned short* Out = is_e ? Eout : Aout;
        #pragma unroll
        for (int ni = 0; ni < 8; ++ni) {
            int colp = colbase + ni * 16 + cc;
            float bb = bias[colp];
            #pragma unroll
            for (int mi = 0; mi < 2; ++mi) {
                #pragma unroll
                for (int i = 0; i < 4; ++i) {
                    int row = rowbase + mi * 16 + cgrp * 4 + i;
                    float x = acc[mi][ni][i] + bb;
                    float v = is_e ? fast_sigmoid(x) : fast_tanh(x);
                    Out[(long)row * 256 + colp] = f2bf(v);
                }
            }
        }
    }
}

// ---------------------------------------------------------------------------
// K2: scan. Block = batch (256 blocks), 512 threads = 8 waves.
// thread (vo=tid>>6, kq=tid&63): owns k-cols 4kq..4kq+3, v in [16vo,16vo+16).
// R5: CHUNK-level double-buffered loads. At the start of each 8-step chunk
// we issue ALL 24 loads (w,e,a x 8 steps) for the NEXT chunk into named
// register arrays (compile-time indices). First use is ~3800cy after issue
// => HBM latency fully hidden and the chunk barrier's vmcnt(0) drain is
// free (loads already landed). Reduce unchanged from R4 (conflict-free).
// ---------------------------------------------------------------------------
__global__ __launch_bounds__(512, 1) void k2_scan(
    const float* __restrict__ Mv0,
    const unsigned short* __restrict__ Wws, const unsigned short* __restrict__ Ews,
    const unsigned short* __restrict__ Aws, unsigned short* __restrict__ Rws)
{
    const int b   = blockIdx.x;
    const int tid = threadIdx.x;
    const int kq  = tid & 63;       // lane id = k-quad
    const int vo  = tid >> 6;       // wave id = v-octant

    __shared__ float4 part[8][8][64];   // [t&7][wave][kq] = 64 KiB, conflict-free

    f32x2 Ma[16], Mb[16];
    #pragma unroll
    for (int j = 0; j < 16; ++j) {
        float4 m4 = *(const float4*)(Mv0 + (vo * 16 + j) * DK + kq * 4);
        Ma[j] = (f32x2){m4.x, m4.y};
        Mb[j] = (f32x2){m4.z, m4.w};
    }

    const long pos0 = (long)b * T_SEQ;
    const unsigned int* Wd = (const unsigned int*)Wws;   // [pos][64 dwords]
    const int wslot = vo * 8 + (kq & 7);

    // chunk buffers (named arrays, constant indices only -> registers)
    unsigned int wdA[8], wdB[8];
    uint2 edA[8], edB[8], adA[8], adB[8];

    #pragma unroll
    for (int s = 0; s < 8; ++s) {   // prologue: chunk 0 into A
        long pn = pos0 + s;
        wdA[s] = Wd[pn * 64 + wslot];
        edA[s] = *(const uint2*)(Ews + pn * 256 + kq * 4);
        adA[s] = *(const uint2*)(Aws + pn * 256 + kq * 4);
    }

#define K2_STEP(T, SLOT, WD, ED, AD)                                           \
    {                                                                          \
        const unsigned int wd = WD;                                            \
        const uint2 ed = ED, ad = AD;                                          \
        f32x2 ea = (f32x2){__uint_as_float(ed.x << 16),                        \
                           __uint_as_float(ed.x & 0xffff0000u)};               \
        f32x2 eb = (f32x2){__uint_as_float(ed.y << 16),                        \
                           __uint_as_float(ed.y & 0xffff0000u)};               \
        f32x2 aa = (f32x2){__uint_as_float(ad.x << 16),                        \
                           __uint_as_float(ad.x & 0xffff0000u)};               \
        f32x2 ab = (f32x2){__uint_as_float(ad.y << 16),                        \
                           __uint_as_float(ad.y & 0xffff0000u)};               \
        f32x2 nea = -ea, neb = -eb;                                            \
        f32x2 ra = (f32x2){0.f, 0.f}, rb = (f32x2){0.f, 0.f};                  \
        _Pragma("unroll")                                                      \
        for (int p = 0; p < 8; ++p) {                                          \
            unsigned int d = __builtin_amdgcn_readlane(wd, p);                 \
            float s0 = __uint_as_float(d << 16);                               \
            float s1 = __uint_as_float(d & 0xffff0000u);                       \
            {                                                                  \
                f32x2 s2 = (f32x2){s0, s0};                                    \
                f32x2 ma = Ma[2 * p], mb = Mb[2 * p];                          \
                ra = pk_fma(s2, ma, ra);                                       \
                rb = pk_fma(s2, mb, rb);                                       \
                f32x2 ta = pk_fma(nea, ma, aa);                                \
                f32x2 tb = pk_fma(neb, mb, ab);                                \
                Ma[2 * p] = pk_fma(s2, ta, ma);                                \
                Mb[2 * p] = pk_fma(s2, tb, mb);                                \
            }                                                                  \
            {                                                                  \
                f32x2 s2 = (f32x2){s1, s1};                                    \
                f32x2 ma = Ma[2 * p + 1], mb = Mb[2 * p + 1];                  \
                ra = pk_fma(s2, ma, ra);                                       \
                rb = pk_fma(s2, mb, rb);                                       \
                f32x2 ta = pk_fma(nea, ma, aa);                                \
                f32x2 tb = pk_fma(neb, mb, ab);                                \
                Ma[2 * p + 1] = pk_fma(s2, ta, ma);                            \
                Mb[2 * p + 1] = pk_fma(s2, tb, mb);                            \
            }                                                                  \
        }                                                                      \
        part[SLOT][vo][kq] = float4{ra.x, ra.y, rb.x, rb.y};                   \
    }

    // One chunk: issue next chunk's 24 loads, compute 8 steps from current
    // regs, then barrier + distributed reduce + barrier.
#define K2_CHUNK(TC, WC, EC, AC, WN, EN, AN)                                   \
    {                                                                          \
        _Pragma("unroll")                                                      \
        for (int s = 0; s < 8; ++s) {                                          \
            long pn = pos0 + ((TC) + 8 + s < T_SEQ ? (TC) + 8 + s : T_SEQ - 1);\
            WN[s] = Wd[pn * 64 + wslot];                                       \
            EN[s] = *(const uint2*)(Ews + pn * 256 + kq * 4);                  \
            AN[s] = *(const uint2*)(Aws + pn * 256 + kq * 4);                  \
        }                                                                      \
        K2_STEP((TC) + 0, 0, WC[0], EC[0], AC[0])                              \
        K2_STEP((TC) + 1, 1, WC[1], EC[1], AC[1])                              \
        K2_STEP((TC) + 2, 2, WC[2], EC[2], AC[2])                              \
        K2_STEP((TC) + 3, 3, WC[3], EC[3], AC[3])                              \
        K2_STEP((TC) + 4, 4, WC[4], EC[4], AC[4])                              \
        K2_STEP((TC) + 5, 5, WC[5], EC[5], AC[5])                              \
        K2_STEP((TC) + 6, 6, WC[6], EC[6], AC[6])                              \
        K2_STEP((TC) + 7, 7, WC[7], EC[7], AC[7])                              \
        __syncthreads();                                                       \
        {   /* wave vo reduces time-slot vo over the 8 waves' partials */      \
            float4 s4 = part[vo][0][kq];                                       \
            _Pragma("unroll")                                                  \
            for (int w2 = 1; w2 < 8; ++w2) {                                   \
                float4 r = part[vo][w2][kq];                                   \
                s4.x += r.x; s4.y += r.y; s4.z += r.z; s4.w += r.w;            \
            }                                                                  \
            ushort4 o;                                                         \
            o.x = f2bf(s4.x); o.y = f2bf(s4.y);                                \
            o.z = f2bf(s4.z); o.w = f2bf(s4.w);                                \
            *(ushort4*)(Rws + (pos0 + (TC) + vo) * 256 + kq * 4) = o;          \
        }                                                                      \
        __syncthreads();                                                       \
    }

    for (int tc = 0; tc < T_SEQ; tc += 16) {
        K2_CHUNK(tc,     wdA, edA, adA, wdB, edB, adB)
        K2_CHUNK(tc + 8, wdB, edB, adB, wdA, edA, adA)
    }
#undef K2_CHUNK
#undef K2_STEP
}

// ---------------------------------------------------------------------------
// K3: f = tanh([reads | k] @ f_W^T + f_b). K=512.
// ---------------------------------------------------------------------------
__global__ __launch_bounds__(256) void k3_f(
    const int* __restrict__ item_seq,
    const unsigned short* __restrict__ k_bf,
    const unsigned short* __restrict__ fW_bf, const float* __restrict__ f_b,
    const unsigned short* __restrict__ Rws,
    unsigned short* __restrict__ Fout)
{
    const int m_tile = blockIdx.x;   // 0..1023
    const int nt  = blockIdx.y;      // 0..1
    const int tid = threadIdx.x;
    const int lane = tid & 63;
    const int wv   = tid >> 6;

    __shared__ int idx_s[128];
    __shared__ unsigned short A_s[128 * 40];
    __shared__ unsigned short B_s[128 * 40];

    if (tid < 128) idx_s[tid] = item_seq[m_tile * 128 + tid];
    __syncthreads();

    int myrow[4], myc4[4], myidx[4];
    #pragma unroll
    for (int j = 0; j < 4; ++j) {
        int chunk = tid + 256 * j;
        myrow[j] = chunk >> 3;
        myc4[j]  = chunk & 7;
        myidx[j] = idx_s[myrow[j]];
    }

    f32x4 acc[2][8];
    #pragma unroll
    for (int mi = 0; mi < 2; ++mi)
        #pragma unroll
        for (int ni = 0; ni < 8; ++ni)
            acc[mi][ni] = (f32x4){0.f, 0.f, 0.f, 0.f};

    for (int bk = 0; bk < 16; ++bk) {
        int k0 = bk * 32;
        #pragma unroll
        for (int j = 0; j < 4; ++j) {
            int row = myrow[j], c4 = myc4[j];
            ushort4 ap;
            if (k0 < 256) {
                long pos = (long)m_tile * 128 + row;
                ap = *(const ushort4*)(Rws + pos * 256 + k0 + c4 * 4);
            } else {
                ap = *(const ushort4*)(k_bf + (long)myidx[j] * DK + (k0 - 256) + c4 * 4);
            }
            *(ushort4*)&A_s[row * 40 + c4 * 4] = ap;
            *(ushort4*)&B_s[row * 40 + c4 * 4] =
                *(const ushort4*)(fW_bf + (long)(nt * 128 + row) * 512 + k0 + c4 * 4);
        }
        __syncthreads();

        const int kq = lane >> 4;
        const int rr = lane & 15;
        bf16x8 af[2], bfr[8];
        #pragma unroll
        for (int mi = 0; mi < 2; ++mi)
            af[mi] = *(const bf16x8*)&A_s[(wv * 32 + mi * 16 + rr) * 40 + kq * 8];
        #pragma unroll
        for (int ni = 0; ni < 8; ++ni)
            bfr[ni] = *(const bf16x8*)&B_s[(ni * 16 + rr) * 40 + kq * 8];
        #pragma unroll
        for (int ni = 0; ni < 8; ++ni)
            #pragma unroll
            for (int mi = 0; mi < 2; ++mi)
                acc[mi][ni] = __builtin_amdgcn_mfma_f32_16x16x32_bf16(
                    af[mi], bfr[ni], acc[mi][ni], 0, 0, 0);
        __syncthreads();
    }

    const int rowbase = m_tile * 128 + wv * 32;
    const int cgrp = lane >> 4;
    const int cc   = lane & 15;
    #pragma unroll
    for (int ni = 0; ni < 8; ++ni) {
        int colp = nt * 128 + ni * 16 + cc;
        float bb = f_b[colp];
        #pragma unroll
        for (int mi = 0; mi < 2; ++mi) {
            #pragma unroll
            for (int i = 0; i < 4; ++i) {
                int row = rowbase + mi * 16 + cgrp * 4 + i;
                Fout[(long)row * 256 + colp] = f2bf(fast_tanh(acc[mi][ni][i] + bb));
            }
        }
    }
}

// ---------------------------------------------------------------------------
// K4: predict = sigmoid(f . p_W + p_b). One wave per 64 consecutive rows.
// ---------------------------------------------------------------------------
__global__ __launch_bounds__(256) void k4_pred(
    const unsigned short* __restrict__ Fws,
    const float* __restrict__ p_W, const float* __restrict__ p_b,
    float* __restrict__ out)
{
    const int tid  = threadIdx.x;
    const int lane = tid & 63;
    const int wgid = blockIdx.x * 4 + (tid >> 6);   // 0..2047
    const float4 pw = *(const float4*)(p_W + lane * 4);
    const float pb = p_b[0];
    #pragma unroll 4
    for (int r = 0; r < 64; ++r) {
        long row = (long)wgid * 64 + r;
        ushort4 q = *(const ushort4*)(Fws + row * 256 + lane * 4);
        float partial = bf2f(q.x) * pw.x + bf2f(q.y) * pw.y
                      + bf2f(q.z) * pw.z + bf2f(q.w) * pw.w;
        #pragma unroll
        for (int off = 32; off >= 1; off >>= 1) partial += __shfl_xor(partial, off);
        if (lane == 0) out[row] = fast_sigmoid(partial + pb);
    }
}

// ---------------------------------------------------------------------------
extern "C" void kernel_launch(void* const* d_in, const int* in_sizes, int n_in,
                              void* d_out, int out_size, void* d_ws, size_t ws_size,
                              hipStream_t stream)
{
    const int*   item_seq    = (const int*)d_in[0];
    const int*   correct_seq = (const int*)d_in[1];
    const float* k_emb = (const float*)d_in[2];
    const float* v_emb = (const float*)d_in[3];
    const float* Mk    = (const float*)d_in[4];
    const float* Mv0   = (const float*)d_in[5];
    const float* e_W   = (const float*)d_in[6];
    const float* e_b   = (const float*)d_in[7];
    const float* a_W   = (const float*)d_in[8];
    const float* a_b   = (const float*)d_in[9];
    const float* f_W   = (const float*)d_in[10];
    const float* f_b   = (const float*)d_in[11];
    const float* p_W   = (const float*)d_in[12];
    const float* p_b   = (const float*)d_in[13];
    float* out = (float*)d_out;

    // ws layout (bytes):
    //   [0,   32M)  Wws  w bf16 [BT][128]     (k3 tables re-use this after k2)
    //   [32M, 96M)  Ews  e bf16 [BT][256]     (aliased by f = k3 output)
    //   [96M, 160M) Aws  a bf16 [BT][256]
    //   [160M,224M) Rws  reads bf16 [BT][256] (k1 bf16 tables live here pre-k2)
    char* ws = (char*)d_ws;
    unsigned short* Wws = (unsigned short*)(ws);
    unsigned short* Ews = (unsigned short*)(ws + 33554432ll);
    unsigned short* Aws = (unsigned short*)(ws + 100663296ll);
    unsigned short* Rws = (unsigned short*)(ws + 167772160ll);

    // k1-phase bf16 tables, parked in the (still dead) Rws region
    unsigned short* kA_bf = Rws;                 // 512000
    unsigned short* v_bf  = Rws + 512000;        // 1024000
    unsigned short* Mk_bf = Rws + 1536000;       // 32768
    unsigned short* eW_bf = Rws + 1568768;       // 65536
    unsigned short* aW_bf = Rws + 1634304;       // 65536
    // k3-phase bf16 tables, parked in the (dead after k2) Wws region
    unsigned short* k3_bf = Wws;                 // 512000
    unsigned short* fW_bf = Wws + 512000;        // 131072

    k0_cvt<<<dim3(1000, 5), dim3(256), 0, stream>>>(
        k_emb, v_emb, Mk, e_W, a_W,
        kA_bf, v_bf, Mk_bf, eW_bf, aW_bf,
        512000, 1024000, 32768, 65536, 65536);

    k1_wea<<<dim3(1024, 5), dim3(256), 0, stream>>>(
        item_seq, correct_seq, kA_bf, v_bf, Mk_bf, eW_bf, e_b, aW_bf, a_b,
        Wws, Ews, Aws);

    k2_scan<<<dim3(256), dim3(512), 0, stream>>>(Mv0, Wws, Ews, Aws, Rws);

    k0_cvt<<<dim3(500, 2), dim3(256), 0, stream>>>(
        k_emb, f_W, nullptr, nullptr, nullptr,
        k3_bf, fW_bf, nullptr, nullptr, nullptr,
        512000, 131072, 0, 0, 0);

    k3_f<<<dim3(1024, 2), dim3(256), 0, stream>>>(
        item_seq, k3_bf, fW_bf, f_b, Rws, Ews /* f overwrites e */);

    k4_pred<<<dim3(512), dim3(256), 0, stream>>>(Ews, p_W, p_b, out);
}

// Round 6
// 533.547 us; speedup vs baseline: 1.0825x; 1.0825x over previous
//
#include <hip/hip_runtime.h>
#include <hip/hip_bf16.h>

// DKVMN fused pipeline for MI355X (gfx950)
// B=256, T=512, DIM_KEY=256, DIM_VALUE=128, NUM_ITEM=2000
// k0_cvt : f32 tables -> bf16 tables in ws
// k1_wea : gather + [Mk|e_W|a_W] GEMM (bf16 MFMA) + softmax/sigmoid/tanh -> ws
// k2_scan: per-batch scan, split into 2 blocks/batch along k (512 blocks =
//          2/CU = 4 waves/SIMD). M state 32 VGPR/thread; per-step distance-2
//          prefetch (R4-proven); chunked conflict-free LDS reduce.
//          R5 lesson: NO big register load-buffer arrays (spills at VGPR>128).
// k3_f   : [reads|k] @ f_W^T GEMM (bf16 MFMA) + tanh -> ws (aliases e)
// k4_pred: sigmoid(f . p_W + p_b) -> d_out (f32)

#define T_SEQ 512
#define DK    256
#define DV    128
#define NITEM 2000
#define BT    131072   // 256*512

typedef __attribute__((ext_vector_type(8))) short bf16x8;
typedef __attribute__((ext_vector_type(4))) float f32x4;
typedef __attribute__((ext_vector_type(2))) float f32x2;

__device__ __forceinline__ float bf2f(unsigned short u) {
    return __uint_as_float(((unsigned int)u) << 16);
}
__device__ __forceinline__ unsigned short f2bf(float x) {   // RNE f32->bf16
    unsigned int u = __float_as_uint(x);
    return (unsigned short)((u + 0x7fffu + ((u >> 16) & 1u)) >> 16);
}
__device__ __forceinline__ float fast_rcp(float x) { return __builtin_amdgcn_rcpf(x); }
__device__ __forceinline__ float fast_sigmoid(float x) { return fast_rcp(1.f + __expf(-x)); }
__device__ __forceinline__ float fast_tanh(float x) {
    float t = __expf(2.f * x);
    return (t - 1.f) * fast_rcp(t + 1.f);
}

// 2xf32 fma helper (NOTE R2: v_pk_fma_f32 is throughput-neutral on CDNA4;
// this is for brevity, the compiler may scalarize freely).
__device__ __forceinline__ f32x2 pk_fma(f32x2 a, f32x2 b, f32x2 c) {
#if __has_builtin(__builtin_elementwise_fma)
    return __builtin_elementwise_fma(a, b, c);
#else
    f32x2 d; d.x = fmaf(a.x, b.x, c.x); d.y = fmaf(a.y, b.y, c.y); return d;
#endif
}

// ---------------------------------------------------------------------------
// k0: f32 -> bf16 table conversion (up to 5 tables per launch, y = table id)
// ---------------------------------------------------------------------------
__global__ __launch_bounds__(256) void k0_cvt(
    const float* __restrict__ s0, const float* __restrict__ s1,
    const float* __restrict__ s2, const float* __restrict__ s3,
    const float* __restrict__ s4,
    unsigned short* __restrict__ d0, unsigned short* __restrict__ d1,
    unsigned short* __restrict__ d2, unsigned short* __restrict__ d3,
    unsigned short* __restrict__ d4,
    int n0, int n1, int n2, int n3, int n4)
{
    const float* s; unsigned short* d; int n;
    switch (blockIdx.y) {
        case 0:  s = s0; d = d0; n = n0; break;
        case 1:  s = s1; d = d1; n = n1; break;
        case 2:  s = s2; d = d2; n = n2; break;
        case 3:  s = s3; d = d3; n = n3; break;
        default: s = s4; d = d4; n = n4; break;
    }
    int i4 = (blockIdx.x * 256 + threadIdx.x) * 4;
    if (i4 < n) {
        float4 v = *(const float4*)(s + i4);
        ushort4 o;
        o.x = f2bf(v.x); o.y = f2bf(v.y); o.z = f2bf(v.z); o.w = f2bf(v.w);
        *(ushort4*)(d + i4) = o;
    }
}

// ---------------------------------------------------------------------------
// K1: 128 rows x 128 cols per block, 4 waves stacked by rows.
// ---------------------------------------------------------------------------
__global__ __launch_bounds__(256) void k1_wea(
    const int* __restrict__ item_seq, const int* __restrict__ correct_seq,
    const unsigned short* __restrict__ k_bf, const unsigned short* __restrict__ v_bf,
    const unsigned short* __restrict__ Mk_bf,
    const unsigned short* __restrict__ eW_bf, const float* __restrict__ e_b,
    const unsigned short* __restrict__ aW_bf, const float* __restrict__ a_b,
    unsigned short* __restrict__ Wout, unsigned short* __restrict__ Eout,
    unsigned short* __restrict__ Aout)
{
    const int m_tile = blockIdx.x;   // 0..1023
    const int n_tile = blockIdx.y;   // 0..4
    const int tid  = threadIdx.x;
    const int lane = tid & 63;
    const int wv   = tid >> 6;

    __shared__ int idx_s[128];
    __shared__ unsigned short A_s[128 * 40];
    __shared__ unsigned short B_s[128 * 40];

    const unsigned short* Atab = (n_tile == 0) ? k_bf : v_bf;
    const unsigned short* Wtab; int wrow0;
    if (n_tile == 0)      { Wtab = Mk_bf; wrow0 = 0;   }
    else if (n_tile == 1) { Wtab = eW_bf; wrow0 = 0;   }
    else if (n_tile == 2) { Wtab = eW_bf; wrow0 = 128; }
    else if (n_tile == 3) { Wtab = aW_bf; wrow0 = 0;   }
    else                  { Wtab = aW_bf; wrow0 = 128; }

    if (tid < 128) {
        int pos = m_tile * 128 + tid;
        int it = item_seq[pos];
        int co = correct_seq[pos];
        idx_s[tid] = (n_tile == 0) ? it : (it + NITEM * co);
    }
    __syncthreads();

    int myrow[4], myc4[4], myidx[4];
    #pragma unroll
    for (int j = 0; j < 4; ++j) {
        int chunk = tid + 256 * j;
        myrow[j] = chunk >> 3;
        myc4[j]  = chunk & 7;
        myidx[j] = idx_s[myrow[j]];
    }

    f32x4 acc[2][8];
    #pragma unroll
    for (int mi = 0; mi < 2; ++mi)
        #pragma unroll
        for (int ni = 0; ni < 8; ++ni)
            acc[mi][ni] = (f32x4){0.f, 0.f, 0.f, 0.f};

    for (int bk = 0; bk < 8; ++bk) {
        int k0 = bk * 32;
        #pragma unroll
        for (int j = 0; j < 4; ++j) {
            int row = myrow[j], c4 = myc4[j];
            *(ushort4*)&A_s[row * 40 + c4 * 4] =
                *(const ushort4*)(Atab + (long)myidx[j] * DK + k0 + c4 * 4);
            *(ushort4*)&B_s[row * 40 + c4 * 4] =
                *(const ushort4*)(Wtab + (long)(wrow0 + row) * DK + k0 + c4 * 4);
        }
        __syncthreads();

        const int kq = lane >> 4;   // k-slot 0..3 (8 bf16 each)
        const int rr = lane & 15;
        bf16x8 af[2], bfr[8];
        #pragma unroll
        for (int mi = 0; mi < 2; ++mi)
            af[mi] = *(const bf16x8*)&A_s[(wv * 32 + mi * 16 + rr) * 40 + kq * 8];
        #pragma unroll
        for (int ni = 0; ni < 8; ++ni)
            bfr[ni] = *(const bf16x8*)&B_s[(ni * 16 + rr) * 40 + kq * 8];
        #pragma unroll
        for (int ni = 0; ni < 8; ++ni)
            #pragma unroll
            for (int mi = 0; mi < 2; ++mi)
                acc[mi][ni] = __builtin_amdgcn_mfma_f32_16x16x32_bf16(
                    af[mi], bfr[ni], acc[mi][ni], 0, 0, 0);
        __syncthreads();
    }

    // C/D layout: col = lane&15, row = (lane>>4)*4 + reg (m89-verified)
    const int rowbase = m_tile * 128 + wv * 32;
    const int cgrp = lane >> 4;
    const int cc   = lane & 15;

    if (n_tile == 0) {
        #pragma unroll
        for (int mi = 0; mi < 2; ++mi) {
            #pragma unroll
            for (int i = 0; i < 4; ++i) {
                float m = -1e30f;
                #pragma unroll
                for (int ni = 0; ni < 8; ++ni) m = fmaxf(m, acc[mi][ni][i]);
                m = fmaxf(m, __shfl_xor(m, 1));
                m = fmaxf(m, __shfl_xor(m, 2));
                m = fmaxf(m, __shfl_xor(m, 4));
                m = fmaxf(m, __shfl_xor(m, 8));
                float p[8]; float s = 0.f;
                #pragma unroll
                for (int ni = 0; ni < 8; ++ni) { p[ni] = __expf(acc[mi][ni][i] - m); s += p[ni]; }
                s += __shfl_xor(s, 1); s += __shfl_xor(s, 2);
                s += __shfl_xor(s, 4); s += __shfl_xor(s, 8);
                float inv = fast_rcp(s);
                int row = rowbase + mi * 16 + cgrp * 4 + i;
                #pragma unroll
                for (int ni = 0; ni < 8; ++ni)
                    Wout[(long)row * 128 + ni * 16 + cc] = f2bf(p[ni] * inv);
            }
        }
    } else {
        const bool is_e = (n_tile <= 2);
        const float* bias = is_e ? e_b : a_b;
        const int colbase = (is_e ? (n_tile - 1) : (n_tile - 3)) * 128;
        unsigned short* Out = is_e ? Eout : Aout;
        #pragma unroll
        for (int ni = 0; ni < 8; ++ni) {
            int colp = colbase + ni * 16 + cc;
            float bb = bias[colp];
            #pragma unroll
            for (int mi = 0; mi < 2; ++mi) {
                #pragma unroll
                for (int i = 0; i < 4; ++i) {
                    int row = rowbase + mi * 16 + cgrp * 4 + i;
                    float x = acc[mi][ni][i] + bb;
                    float v = is_e ? fast_sigmoid(x) : fast_tanh(x);
                    Out[(long)row * 256 + colp] = f2bf(v);
                }
            }
        }
    }
}

// ---------------------------------------------------------------------------
// K2: scan. 512 blocks = (batch b, k-half kh); 2 blocks/CU, 512 thr = 8 waves.
// thread (vo=tid>>6, kq=tid&63): owns k-cols kh*128+2kq..+1, v in [16vo,+16).
// M state = 16 x f32x2 = 32 VGPR. Per-step distance-2 prefetch via two named
// scalar sets (A/B) -- no buffer arrays (R5 spill lesson). Reduce: per step
// one contiguous ds_write_b64 part[t&7][vo][kq]; every 8 steps barrier +
// wave vo sums slot vo (8 ds_read_b64) + coalesced Rws store + barrier.
// ---------------------------------------------------------------------------
__global__ __launch_bounds__(512, 4) void k2_scan(
    const float* __restrict__ Mv0,
    const unsigned short* __restrict__ Wws, const unsigned short* __restrict__ Ews,
    const unsigned short* __restrict__ Aws, unsigned short* __restrict__ Rws)
{
    const int b   = blockIdx.x >> 1;
    const int kh  = blockIdx.x & 1;   // k-half: cols [kh*128, kh*128+128)
    const int tid = threadIdx.x;
    const int kq  = tid & 63;         // lane id; my cols = kh*128 + 2kq, +1
    const int vo  = tid >> 6;         // wave id = v-octant

    __shared__ f32x2 part[8][8][64];  // [t&7][wave][kq] = 32 KiB, conflict-free

    f32x2 M[16];
    #pragma unroll
    for (int j = 0; j < 16; ++j) {
        float2 m2 = *(const float2*)(Mv0 + (vo * 16 + j) * DK + kh * 128 + kq * 2);
        M[j] = (f32x2){m2.x, m2.y};
    }

    const long pos0 = (long)b * T_SEQ;
    const unsigned int* Wd = (const unsigned int*)Wws;   // [pos][64 dwords]
    const unsigned int* Ed = (const unsigned int*)Ews;   // [pos][128 dwords]
    const unsigned int* Ad = (const unsigned int*)Aws;
    const int wslot = vo * 8 + (kq & 7);
    const int eslot = kh * 64 + kq;

    // distance-2 prefetch, named scalar sets (A/B) only
    unsigned int wdA = Wd[(pos0 + 0) * 64 + wslot];
    unsigned int edA = Ed[(pos0 + 0) * 128 + eslot];
    unsigned int adA = Ad[(pos0 + 0) * 128 + eslot];
    unsigned int wdB = Wd[(pos0 + 1) * 64 + wslot];
    unsigned int edB = Ed[(pos0 + 1) * 128 + eslot];
    unsigned int adB = Ad[(pos0 + 1) * 128 + eslot];

#define K2_STEP(T, SLOT, WD, ED, AD)                                           \
    {                                                                          \
        const unsigned int wd = WD;                                            \
        const unsigned int ed = ED, ad = AD;                                   \
        {   /* issue t+2 loads immediately: ~2 bodies of latency cover */      \
            long pn = pos0 + ((T) + 2 < T_SEQ ? (T) + 2 : T_SEQ - 1);          \
            WD = Wd[pn * 64 + wslot];                                          \
            ED = Ed[pn * 128 + eslot];                                         \
            AD = Ad[pn * 128 + eslot];                                         \
        }                                                                      \
        f32x2 ea = (f32x2){__uint_as_float(ed << 16),                          \
                           __uint_as_float(ed & 0xffff0000u)};                 \
        f32x2 aa = (f32x2){__uint_as_float(ad << 16),                          \
                           __uint_as_float(ad & 0xffff0000u)};                 \
        f32x2 nea = -ea;                                                       \
        f32x2 r = (f32x2){0.f, 0.f};                                           \
        _Pragma("unroll")                                                      \
        for (int p = 0; p < 8; ++p) {                                          \
            unsigned int d = __builtin_amdgcn_readlane(wd, p);                 \
            float s0 = __uint_as_float(d << 16);                               \
            float s1 = __uint_as_float(d & 0xffff0000u);                       \
            {                                                                  \
                f32x2 s2 = (f32x2){s0, s0};                                    \
                f32x2 m = M[2 * p];                                            \
                r = pk_fma(s2, m, r);              /* read before update */    \
                f32x2 t2 = pk_fma(nea, m, aa);     /* a - e*M */               \
                M[2 * p] = pk_fma(s2, t2, m);      /* M + w*(a - e*M) */       \
            }                                                                  \
            {                                                                  \
                f32x2 s2 = (f32x2){s1, s1};                                    \
                f32x2 m = M[2 * p + 1];                                        \
                r = pk_fma(s2, m, r);                                          \
                f32x2 t2 = pk_fma(nea, m, aa);                                 \
                M[2 * p + 1] = pk_fma(s2, t2, m);                              \
            }                                                                  \
        }                                                                      \
        part[SLOT][vo][kq] = r;                                                \
    }

    for (int tc = 0; tc < T_SEQ; tc += 8) {
        K2_STEP(tc + 0, 0, wdA, edA, adA)
        K2_STEP(tc + 1, 1, wdB, edB, adB)
        K2_STEP(tc + 2, 2, wdA, edA, adA)
        K2_STEP(tc + 3, 3, wdB, edB, adB)
        K2_STEP(tc + 4, 4, wdA, edA, adA)
        K2_STEP(tc + 5, 5, wdB, edB, adB)
        K2_STEP(tc + 6, 6, wdA, edA, adA)
        K2_STEP(tc + 7, 7, wdB, edB, adB)
        __syncthreads();
        {   // wave vo reduces time-slot vo over the 8 waves' partials
            f32x2 s = part[vo][0][kq];
            #pragma unroll
            for (int w2 = 1; w2 < 8; ++w2) {
                f32x2 r = part[vo][w2][kq];
                s.x += r.x; s.y += r.y;
            }
            ushort2 o;
            o.x = f2bf(s.x); o.y = f2bf(s.y);
            *(ushort2*)(Rws + (pos0 + tc + vo) * 256 + kh * 128 + kq * 2) = o;
        }
        __syncthreads();
    }
#undef K2_STEP
}

// ---------------------------------------------------------------------------
// K3: f = tanh([reads | k] @ f_W^T + f_b). K=512.
// ---------------------------------------------------------------------------
__global__ __launch_bounds__(256) void k3_f(
    const int* __restrict__ item_seq,
    const unsigned short* __restrict__ k_bf,
    const unsigned short* __restrict__ fW_bf, const float* __restrict__ f_b,
    const unsigned short* __restrict__ Rws,
    unsigned short* __restrict__ Fout)
{
    const int m_tile = blockIdx.x;   // 0..1023
    const int nt  = blockIdx.y;      // 0..1
    const int tid = threadIdx.x;
    const int lane = tid & 63;
    const int wv   = tid >> 6;

    __shared__ int idx_s[128];
    __shared__ unsigned short A_s[128 * 40];
    __shared__ unsigned short B_s[128 * 40];

    if (tid < 128) idx_s[tid] = item_seq[m_tile * 128 + tid];
    __syncthreads();

    int myrow[4], myc4[4], myidx[4];
    #pragma unroll
    for (int j = 0; j < 4; ++j) {
        int chunk = tid + 256 * j;
        myrow[j] = chunk >> 3;
        myc4[j]  = chunk & 7;
        myidx[j] = idx_s[myrow[j]];
    }

    f32x4 acc[2][8];
    #pragma unroll
    for (int mi = 0; mi < 2; ++mi)
        #pragma unroll
        for (int ni = 0; ni < 8; ++ni)
            acc[mi][ni] = (f32x4){0.f, 0.f, 0.f, 0.f};

    for (int bk = 0; bk < 16; ++bk) {
        int k0 = bk * 32;
        #pragma unroll
        for (int j = 0; j < 4; ++j) {
            int row = myrow[j], c4 = myc4[j];
            ushort4 ap;
            if (k0 < 256) {
                long pos = (long)m_tile * 128 + row;
                ap = *(const ushort4*)(Rws + pos * 256 + k0 + c4 * 4);
            } else {
                ap = *(const ushort4*)(k_bf + (long)myidx[j] * DK + (k0 - 256) + c4 * 4);
            }
            *(ushort4*)&A_s[row * 40 + c4 * 4] = ap;
            *(ushort4*)&B_s[row * 40 + c4 * 4] =
                *(const ushort4*)(fW_bf + (long)(nt * 128 + row) * 512 + k0 + c4 * 4);
        }
        __syncthreads();

        const int kq = lane >> 4;
        const int rr = lane & 15;
        bf16x8 af[2], bfr[8];
        #pragma unroll
        for (int mi = 0; mi < 2; ++mi)
            af[mi] = *(const bf16x8*)&A_s[(wv * 32 + mi * 16 + rr) * 40 + kq * 8];
        #pragma unroll
        for (int ni = 0; ni < 8; ++ni)
            bfr[ni] = *(const bf16x8*)&B_s[(ni * 16 + rr) * 40 + kq * 8];
        #pragma unroll
        for (int ni = 0; ni < 8; ++ni)
            #pragma unroll
            for (int mi = 0; mi < 2; ++mi)
                acc[mi][ni] = __builtin_amdgcn_mfma_f32_16x16x32_bf16(
                    af[mi], bfr[ni], acc[mi][ni], 0, 0, 0);
        __syncthreads();
    }

    const int rowbase = m_tile * 128 + wv * 32;
    const int cgrp = lane >> 4;
    const int cc   = lane & 15;
    #pragma unroll
    for (int ni = 0; ni < 8; ++ni) {
        int colp = nt * 128 + ni * 16 + cc;
        float bb = f_b[colp];
        #pragma unroll
        for (int mi = 0; mi < 2; ++mi) {
            #pragma unroll
            for (int i = 0; i < 4; ++i) {
                int row = rowbase + mi * 16 + cgrp * 4 + i;
                Fout[(long)row * 256 + colp] = f2bf(fast_tanh(acc[mi][ni][i] + bb));
            }
        }
    }
}

// ---------------------------------------------------------------------------
// K4: predict = sigmoid(f . p_W + p_b). One wave per 64 consecutive rows.
// ---------------------------------------------------------------------------
__global__ __launch_bounds__(256) void k4_pred(
    const unsigned short* __restrict__ Fws,
    const float* __restrict__ p_W, const float* __restrict__ p_b,
    float* __restrict__ out)
{
    const int tid  = threadIdx.x;
    const int lane = tid & 63;
    const int wgid = blockIdx.x * 4 + (tid >> 6);   // 0..2047
    const float4 pw = *(const float4*)(p_W + lane * 4);
    const float pb = p_b[0];
    #pragma unroll 4
    for (int r = 0; r < 64; ++r) {
        long row = (long)wgid * 64 + r;
        ushort4 q = *(const ushort4*)(Fws + row * 256 + lane * 4);
        float partial = bf2f(q.x) * pw.x + bf2f(q.y) * pw.y
                      + bf2f(q.z) * pw.z + bf2f(q.w) * pw.w;
        #pragma unroll
        for (int off = 32; off >= 1; off >>= 1) partial += __shfl_xor(partial, off);
        if (lane == 0) out[row] = fast_sigmoid(partial + pb);
    }
}

// ---------------------------------------------------------------------------
extern "C" void kernel_launch(void* const* d_in, const int* in_sizes, int n_in,
                              void* d_out, int out_size, void* d_ws, size_t ws_size,
                              hipStream_t stream)
{
    const int*   item_seq    = (const int*)d_in[0];
    const int*   correct_seq = (const int*)d_in[1];
    const float* k_emb = (const float*)d_in[2];
    const float* v_emb = (const float*)d_in[3];
    const float* Mk    = (const float*)d_in[4];
    const float* Mv0   = (const float*)d_in[5];
    const float* e_W   = (const float*)d_in[6];
    const float* e_b   = (const float*)d_in[7];
    const float* a_W   = (const float*)d_in[8];
    const float* a_b   = (const float*)d_in[9];
    const float* f_W   = (const float*)d_in[10];
    const float* f_b   = (const float*)d_in[11];
    const float* p_W   = (const float*)d_in[12];
    const float* p_b   = (const float*)d_in[13];
    float* out = (float*)d_out;

    // ws layout (bytes):
    //   [0,   32M)  Wws  w bf16 [BT][128]     (k3 tables re-use this after k2)
    //   [32M, 96M)  Ews  e bf16 [BT][256]     (aliased by f = k3 output)
    //   [96M, 160M) Aws  a bf16 [BT][256]
    //   [160M,224M) Rws  reads bf16 [BT][256] (k1 bf16 tables live here pre-k2)
    char* ws = (char*)d_ws;
    unsigned short* Wws = (unsigned short*)(ws);
    unsigned short* Ews = (unsigned short*)(ws + 33554432ll);
    unsigned short* Aws = (unsigned short*)(ws + 100663296ll);
    unsigned short* Rws = (unsigned short*)(ws + 167772160ll);

    // k1-phase bf16 tables, parked in the (still dead) Rws region
    unsigned short* kA_bf = Rws;                 // 512000
    unsigned short* v_bf  = Rws + 512000;        // 1024000
    unsigned short* Mk_bf = Rws + 1536000;       // 32768
    unsigned short* eW_bf = Rws + 1568768;       // 65536
    unsigned short* aW_bf = Rws + 1634304;       // 65536
    // k3-phase bf16 tables, parked in the (dead after k2) Wws region
    unsigned short* k3_bf = Wws;                 // 512000
    unsigned short* fW_bf = Wws + 512000;        // 131072

    k0_cvt<<<dim3(1000, 5), dim3(256), 0, stream>>>(
        k_emb, v_emb, Mk, e_W, a_W,
        kA_bf, v_bf, Mk_bf, eW_bf, aW_bf,
        512000, 1024000, 32768, 65536, 65536);

    k1_wea<<<dim3(1024, 5), dim3(256), 0, stream>>>(
        item_seq, correct_seq, kA_bf, v_bf, Mk_bf, eW_bf, e_b, aW_bf, a_b,
        Wws, Ews, Aws);

    k2_scan<<<dim3(512), dim3(512), 0, stream>>>(Mv0, Wws, Ews, Aws, Rws);

    k0_cvt<<<dim3(500, 2), dim3(256), 0, stream>>>(
        k_emb, f_W, nullptr, nullptr, nullptr,
        k3_bf, fW_bf, nullptr, nullptr, nullptr,
        512000, 131072, 0, 0, 0);

    k3_f<<<dim3(1024, 2), dim3(256), 0, stream>>>(
        item_seq, k3_bf, fW_bf, f_b, Rws, Ews /* f overwrites e */);

    k4_pred<<<dim3(512), dim3(256), 0, stream>>>(Ews, p_W, p_b, out);
}

// Round 7
// 483.567 us; speedup vs baseline: 1.1944x; 1.1034x over previous
//
#include <hip/hip_runtime.h>
#include <hip/hip_bf16.h>
#include <hip/hip_fp16.h>

// DKVMN fused pipeline for MI355X (gfx950)
// B=256, T=512, DIM_KEY=256, DIM_VALUE=128, NUM_ITEM=2000
// k0_cvt : f32 tables -> bf16 tables in ws (MFMA operands)
// k1_wea : gather + [Mk|e_W|a_W] GEMM (bf16 MFMA); outputs w/e/a as F16
// k2_scan: per-batch scan in f16 packed math: M state = h16x2 v-pairs
//          (4 k-cols x 8 pairs = 32 VGPR), v_dot2_f32_f16 for reads,
//          v_pk_fma_f16 for updates (2x f32 rate). 256 blocks, dist-4
//          prefetch (named sets, no arrays -> no spill), R4 chunked reduce.
// k3_f   : [reads|k] @ f_W^T GEMM (bf16 MFMA) + tanh -> ws (aliases e)
// k4_pred: sigmoid(f . p_W + p_b) -> d_out (f32)

#define T_SEQ 512
#define DK    256
#define DV    128
#define NITEM 2000
#define BT    131072   // 256*512

typedef __attribute__((ext_vector_type(8))) short bf16x8;
typedef __attribute__((ext_vector_type(4))) float f32x4;
typedef _Float16 h16x2 __attribute__((ext_vector_type(2)));
typedef _Float16 h16x4 __attribute__((ext_vector_type(4)));

__device__ __forceinline__ float bf2f(unsigned short u) {
    return __uint_as_float(((unsigned int)u) << 16);
}
__device__ __forceinline__ unsigned short f2bf(float x) {   // RNE f32->bf16
    unsigned int u = __float_as_uint(x);
    return (unsigned short)((u + 0x7fffu + ((u >> 16) & 1u)) >> 16);
}
__device__ __forceinline__ unsigned short f2h(float x) {    // f32->f16
    _Float16 h = (_Float16)x;
    return __builtin_bit_cast(unsigned short, h);
}
__device__ __forceinline__ float fast_rcp(float x) { return __builtin_amdgcn_rcpf(x); }
__device__ __forceinline__ float fast_sigmoid(float x) { return fast_rcp(1.f + __expf(-x)); }
__device__ __forceinline__ float fast_tanh(float x) {
    float t = __expf(2.f * x);
    return (t - 1.f) * fast_rcp(t + 1.f);
}

// v_dot2_f32_f16: r += a.x*b.x + a.y*b.y (f32 accumulate)
__device__ __forceinline__ float fdot2_(h16x2 a, h16x2 b, float c) {
#if __has_builtin(__builtin_amdgcn_fdot2)
    return __builtin_amdgcn_fdot2(a, b, c, false);
#else
    return (float)a[0] * (float)b[0] + (float)a[1] * (float)b[1] + c;
#endif
}
// v_pk_fma_f16
__device__ __forceinline__ h16x2 pkfma(h16x2 a, h16x2 b, h16x2 c) {
#if __has_builtin(__builtin_elementwise_fma)
    return __builtin_elementwise_fma(a, b, c);
#else
    return a * b + c;
#endif
}

// ---------------------------------------------------------------------------
// k0: f32 -> bf16 table conversion (up to 5 tables per launch, y = table id)
// ---------------------------------------------------------------------------
__global__ __launch_bounds__(256) void k0_cvt(
    const float* __restrict__ s0, const float* __restrict__ s1,
    const float* __restrict__ s2, const float* __restrict__ s3,
    const float* __restrict__ s4,
    unsigned short* __restrict__ d0, unsigned short* __restrict__ d1,
    unsigned short* __restrict__ d2, unsigned short* __restrict__ d3,
    unsigned short* __restrict__ d4,
    int n0, int n1, int n2, int n3, int n4)
{
    const float* s; unsigned short* d; int n;
    switch (blockIdx.y) {
        case 0:  s = s0; d = d0; n = n0; break;
        case 1:  s = s1; d = d1; n = n1; break;
        case 2:  s = s2; d = d2; n = n2; break;
        case 3:  s = s3; d = d3; n = n3; break;
        default: s = s4; d = d4; n = n4; break;
    }
    int i4 = (blockIdx.x * 256 + threadIdx.x) * 4;
    if (i4 < n) {
        float4 v = *(const float4*)(s + i4);
        ushort4 o;
        o.x = f2bf(v.x); o.y = f2bf(v.y); o.z = f2bf(v.z); o.w = f2bf(v.w);
        *(ushort4*)(d + i4) = o;
    }
}

// ---------------------------------------------------------------------------
// K1: 128 rows x 128 cols per block, 4 waves stacked by rows.
// Outputs w/e/a as F16 (k2 consumes f16 packed math); GEMM stays bf16 MFMA.
// ---------------------------------------------------------------------------
__global__ __launch_bounds__(256) void k1_wea(
    const int* __restrict__ item_seq, const int* __restrict__ correct_seq,
    const unsigned short* __restrict__ k_bf, const unsigned short* __restrict__ v_bf,
    const unsigned short* __restrict__ Mk_bf,
    const unsigned short* __restrict__ eW_bf, const float* __restrict__ e_b,
    const unsigned short* __restrict__ aW_bf, const float* __restrict__ a_b,
    unsigned short* __restrict__ Wout, unsigned short* __restrict__ Eout,
    unsigned short* __restrict__ Aout)
{
    const int m_tile = blockIdx.x;   // 0..1023
    const int n_tile = blockIdx.y;   // 0..4
    const int tid  = threadIdx.x;
    const int lane = tid & 63;
    const int wv   = tid >> 6;

    __shared__ int idx_s[128];
    __shared__ unsigned short A_s[128 * 40];
    __shared__ unsigned short B_s[128 * 40];

    const unsigned short* Atab = (n_tile == 0) ? k_bf : v_bf;
    const unsigned short* Wtab; int wrow0;
    if (n_tile == 0)      { Wtab = Mk_bf; wrow0 = 0;   }
    else if (n_tile == 1) { Wtab = eW_bf; wrow0 = 0;   }
    else if (n_tile == 2) { Wtab = eW_bf; wrow0 = 128; }
    else if (n_tile == 3) { Wtab = aW_bf; wrow0 = 0;   }
    else                  { Wtab = aW_bf; wrow0 = 128; }

    if (tid < 128) {
        int pos = m_tile * 128 + tid;
        int it = item_seq[pos];
        int co = correct_seq[pos];
        idx_s[tid] = (n_tile == 0) ? it : (it + NITEM * co);
    }
    __syncthreads();

    int myrow[4], myc4[4], myidx[4];
    #pragma unroll
    for (int j = 0; j < 4; ++j) {
        int chunk = tid + 256 * j;
        myrow[j] = chunk >> 3;
        myc4[j]  = chunk & 7;
        myidx[j] = idx_s[myrow[j]];
    }

    f32x4 acc[2][8];
    #pragma unroll
    for (int mi = 0; mi < 2; ++mi)
        #pragma unroll
        for (int ni = 0; ni < 8; ++ni)
            acc[mi][ni] = (f32x4){0.f, 0.f, 0.f, 0.f};

    for (int bk = 0; bk < 8; ++bk) {
        int k0 = bk * 32;
        #pragma unroll
        for (int j = 0; j < 4; ++j) {
            int row = myrow[j], c4 = myc4[j];
            *(ushort4*)&A_s[row * 40 + c4 * 4] =
                *(const ushort4*)(Atab + (long)myidx[j] * DK + k0 + c4 * 4);
            *(ushort4*)&B_s[row * 40 + c4 * 4] =
                *(const ushort4*)(Wtab + (long)(wrow0 + row) * DK + k0 + c4 * 4);
        }
        __syncthreads();

        const int kq = lane >> 4;   // k-slot 0..3 (8 bf16 each)
        const int rr = lane & 15;
        bf16x8 af[2], bfr[8];
        #pragma unroll
        for (int mi = 0; mi < 2; ++mi)
            af[mi] = *(const bf16x8*)&A_s[(wv * 32 + mi * 16 + rr) * 40 + kq * 8];
        #pragma unroll
        for (int ni = 0; ni < 8; ++ni)
            bfr[ni] = *(const bf16x8*)&B_s[(ni * 16 + rr) * 40 + kq * 8];
        #pragma unroll
        for (int ni = 0; ni < 8; ++ni)
            #pragma unroll
            for (int mi = 0; mi < 2; ++mi)
                acc[mi][ni] = __builtin_amdgcn_mfma_f32_16x16x32_bf16(
                    af[mi], bfr[ni], acc[mi][ni], 0, 0, 0);
        __syncthreads();
    }

    // C/D layout: col = lane&15, row = (lane>>4)*4 + reg (m89-verified)
    const int rowbase = m_tile * 128 + wv * 32;
    const int cgrp = lane >> 4;
    const int cc   = lane & 15;

    if (n_tile == 0) {
        #pragma unroll
        for (int mi = 0; mi < 2; ++mi) {
            #pragma unroll
            for (int i = 0; i < 4; ++i) {
                float m = -1e30f;
                #pragma unroll
                for (int ni = 0; ni < 8; ++ni) m = fmaxf(m, acc[mi][ni][i]);
                m = fmaxf(m, __shfl_xor(m, 1));
                m = fmaxf(m, __shfl_xor(m, 2));
                m = fmaxf(m, __shfl_xor(m, 4));
                m = fmaxf(m, __shfl_xor(m, 8));
                float p[8]; float s = 0.f;
                #pragma unroll
                for (int ni = 0; ni < 8; ++ni) { p[ni] = __expf(acc[mi][ni][i] - m); s += p[ni]; }
                s += __shfl_xor(s, 1); s += __shfl_xor(s, 2);
                s += __shfl_xor(s, 4); s += __shfl_xor(s, 8);
                float inv = fast_rcp(s);
                int row = rowbase + mi * 16 + cgrp * 4 + i;
                #pragma unroll
                for (int ni = 0; ni < 8; ++ni)
                    Wout[(long)row * 128 + ni * 16 + cc] = f2h(p[ni] * inv);
            }
        }
    } else {
        const bool is_e = (n_tile <= 2);
        const float* bias = is_e ? e_b : a_b;
        const int colbase = (is_e ? (n_tile - 1) : (n_tile - 3)) * 128;
        unsigned short* Out = is_e ? Eout : Aout;
        #pragma unroll
        for (int ni = 0; ni < 8; ++ni) {
            int colp = colbase + ni * 16 + cc;
            float bb = bias[colp];
            #pragma unroll
            for (int mi = 0; mi < 2; ++mi) {
                #pragma unroll
                for (int i = 0; i < 4; ++i) {
                    int row = rowbase + mi * 16 + cgrp * 4 + i;
                    float x = acc[mi][ni][i] + bb;
                    float v = is_e ? fast_sigmoid(x) : fast_tanh(x);
                    Out[(long)row * 256 + colp] = f2h(v);
                }
            }
        }
    }
}

// ---------------------------------------------------------------------------
// K2: scan, f16 packed. Block = batch (256 blocks), 512 thr = 8 waves.
// thread (vo=tid>>6, kq=tid&63): k-cols 4kq..4kq+3, v-pairs vo*8..vo*8+7
// (v in [16vo,16vo+16)). M = h16x2[4][8] (32 VGPR). Per (pair,col):
//   r += dot2(w_pair, M)         [v_dot2_f32_f16, f32 accum, pre-update]
//   M  = pkfma(w, pkfma(-e,M,a), M)   [2x v_pk_fma_f16, neg folded]
// w dword = natural f16 v-pair; broadcast via readlane (same trick as f32).
// Distance-4 prefetch, named scalar sets A..D (R5 lesson: no arrays).
// Reduce: R4's conflict-free chunked LDS pattern (0 conflicts measured).
// ---------------------------------------------------------------------------
__global__ __launch_bounds__(512, 4) void k2_scan(
    const float* __restrict__ Mv0,
    const unsigned short* __restrict__ Wws, const unsigned short* __restrict__ Ews,
    const unsigned short* __restrict__ Aws, unsigned short* __restrict__ Rws)
{
    const int b   = blockIdx.x;
    const int tid = threadIdx.x;
    const int kq  = tid & 63;       // lane id = k-quad (cols 4kq..4kq+3)
    const int vo  = tid >> 6;       // wave id = v-octant

    __shared__ float4 part[8][8][64];   // [t&7][wave][kq] = 64 KiB

    h16x2 M[4][8];                      // [k-col][v-pair]
    #pragma unroll
    for (int p = 0; p < 8; ++p) {
        const float4 r0 = *(const float4*)(Mv0 + (vo * 16 + 2 * p) * DK + kq * 4);
        const float4 r1 = *(const float4*)(Mv0 + (vo * 16 + 2 * p + 1) * DK + kq * 4);
        M[0][p] = (h16x2){(_Float16)r0.x, (_Float16)r1.x};
        M[1][p] = (h16x2){(_Float16)r0.y, (_Float16)r1.y};
        M[2][p] = (h16x2){(_Float16)r0.z, (_Float16)r1.z};
        M[3][p] = (h16x2){(_Float16)r0.w, (_Float16)r1.w};
    }

    const long pos0 = (long)b * T_SEQ;
    const unsigned int* Wd = (const unsigned int*)Wws;   // [pos][64 dwords]
    const int wslot = vo * 8 + (kq & 7);

    // distance-4 prefetch, named scalar sets only (no spillable arrays)
    unsigned int wdA, wdB, wdC, wdD;
    uint2 edA, edB, edC, edD, adA, adB, adC, adD;
    wdA = Wd[(pos0 + 0) * 64 + wslot];
    edA = *(const uint2*)(Ews + (pos0 + 0) * 256 + kq * 4);
    adA = *(const uint2*)(Aws + (pos0 + 0) * 256 + kq * 4);
    wdB = Wd[(pos0 + 1) * 64 + wslot];
    edB = *(const uint2*)(Ews + (pos0 + 1) * 256 + kq * 4);
    adB = *(const uint2*)(Aws + (pos0 + 1) * 256 + kq * 4);
    wdC = Wd[(pos0 + 2) * 64 + wslot];
    edC = *(const uint2*)(Ews + (pos0 + 2) * 256 + kq * 4);
    adC = *(const uint2*)(Aws + (pos0 + 2) * 256 + kq * 4);
    wdD = Wd[(pos0 + 3) * 64 + wslot];
    edD = *(const uint2*)(Ews + (pos0 + 3) * 256 + kq * 4);
    adD = *(const uint2*)(Aws + (pos0 + 3) * 256 + kq * 4);

#define K2_STEP(T, SLOT, WD, ED, AD)                                           \
    {                                                                          \
        const unsigned int wd = WD;                                            \
        const uint2 ed = ED, ad = AD;                                          \
        {   /* issue t+4 loads: ~4 bodies of latency cover */                  \
            long pn = pos0 + ((T) + 4 < T_SEQ ? (T) + 4 : T_SEQ - 1);          \
            WD = Wd[pn * 64 + wslot];                                          \
            ED = *(const uint2*)(Ews + pn * 256 + kq * 4);                     \
            AD = *(const uint2*)(Aws + pn * 256 + kq * 4);                     \
        }                                                                      \
        const h16x4 ev = __builtin_bit_cast(h16x4, ed);                        \
        const h16x4 av = __builtin_bit_cast(h16x4, ad);                        \
        const h16x2 es0 = (h16x2){ev[0], ev[0]}, as0 = (h16x2){av[0], av[0]};  \
        const h16x2 es1 = (h16x2){ev[1], ev[1]}, as1 = (h16x2){av[1], av[1]};  \
        const h16x2 es2 = (h16x2){ev[2], ev[2]}, as2 = (h16x2){av[2], av[2]};  \
        const h16x2 es3 = (h16x2){ev[3], ev[3]}, as3 = (h16x2){av[3], av[3]};  \
        float r0 = 0.f, r1 = 0.f, r2 = 0.f, r3 = 0.f;                          \
        _Pragma("unroll")                                                      \
        for (int p = 0; p < 8; ++p) {                                          \
            const h16x2 wpk = __builtin_bit_cast(h16x2,                        \
                __builtin_amdgcn_readlane(wd, p));                             \
            r0 = fdot2_(wpk, M[0][p], r0);   /* read BEFORE update */          \
            r1 = fdot2_(wpk, M[1][p], r1);                                     \
            r2 = fdot2_(wpk, M[2][p], r2);                                     \
            r3 = fdot2_(wpk, M[3][p], r3);                                     \
            M[0][p] = pkfma(wpk, pkfma(-es0, M[0][p], as0), M[0][p]);          \
            M[1][p] = pkfma(wpk, pkfma(-es1, M[1][p], as1), M[1][p]);          \
            M[2][p] = pkfma(wpk, pkfma(-es2, M[2][p], as2), M[2][p]);          \
            M[3][p] = pkfma(wpk, pkfma(-es3, M[3][p], as3), M[3][p]);          \
        }                                                                      \
        part[SLOT][vo][kq] = float4{r0, r1, r2, r3};                           \
    }

    for (int tc = 0; tc < T_SEQ; tc += 8) {
        K2_STEP(tc + 0, 0, wdA, edA, adA)
        K2_STEP(tc + 1, 1, wdB, edB, adB)
        K2_STEP(tc + 2, 2, wdC, edC, adC)
        K2_STEP(tc + 3, 3, wdD, edD, adD)
        K2_STEP(tc + 4, 4, wdA, edA, adA)
        K2_STEP(tc + 5, 5, wdB, edB, adB)
        K2_STEP(tc + 6, 6, wdC, edC, adC)
        K2_STEP(tc + 7, 7, wdD, edD, adD)
        __syncthreads();
        {   // wave vo reduces time-slot vo over the 8 waves' partials
            float4 s = part[vo][0][kq];
            #pragma unroll
            for (int w2 = 1; w2 < 8; ++w2) {
                float4 r = part[vo][w2][kq];
                s.x += r.x; s.y += r.y; s.z += r.z; s.w += r.w;
            }
            ushort4 o;
            o.x = f2bf(s.x); o.y = f2bf(s.y); o.z = f2bf(s.z); o.w = f2bf(s.w);
            *(ushort4*)(Rws + (pos0 + tc + vo) * 256 + kq * 4) = o;
        }
        __syncthreads();
    }
#undef K2_STEP
}

// ---------------------------------------------------------------------------
// K3: f = tanh([reads | k] @ f_W^T + f_b). K=512.
// ---------------------------------------------------------------------------
__global__ __launch_bounds__(256) void k3_f(
    const int* __restrict__ item_seq,
    const unsigned short* __restrict__ k_bf,
    const unsigned short* __restrict__ fW_bf, const float* __restrict__ f_b,
    const unsigned short* __restrict__ Rws,
    unsigned short* __restrict__ Fout)
{
    const int m_tile = blockIdx.x;   // 0..1023
    const int nt  = blockIdx.y;      // 0..1
    const int tid = threadIdx.x;
    const int lane = tid & 63;
    const int wv   = tid >> 6;

    __shared__ int idx_s[128];
    __shared__ unsigned short A_s[128 * 40];
    __shared__ unsigned short B_s[128 * 40];

    if (tid < 128) idx_s[tid] = item_seq[m_tile * 128 + tid];
    __syncthreads();

    int myrow[4], myc4[4], myidx[4];
    #pragma unroll
    for (int j = 0; j < 4; ++j) {
        int chunk = tid + 256 * j;
        myrow[j] = chunk >> 3;
        myc4[j]  = chunk & 7;
        myidx[j] = idx_s[myrow[j]];
    }

    f32x4 acc[2][8];
    #pragma unroll
    for (int mi = 0; mi < 2; ++mi)
        #pragma unroll
        for (int ni = 0; ni < 8; ++ni)
            acc[mi][ni] = (f32x4){0.f, 0.f, 0.f, 0.f};

    for (int bk = 0; bk < 16; ++bk) {
        int k0 = bk * 32;
        #pragma unroll
        for (int j = 0; j < 4; ++j) {
            int row = myrow[j], c4 = myc4[j];
            ushort4 ap;
            if (k0 < 256) {
                long pos = (long)m_tile * 128 + row;
                ap = *(const ushort4*)(Rws + pos * 256 + k0 + c4 * 4);
            } else {
                ap = *(const ushort4*)(k_bf + (long)myidx[j] * DK + (k0 - 256) + c4 * 4);
            }
            *(ushort4*)&A_s[row * 40 + c4 * 4] = ap;
            *(ushort4*)&B_s[row * 40 + c4 * 4] =
                *(const ushort4*)(fW_bf + (long)(nt * 128 + row) * 512 + k0 + c4 * 4);
        }
        __syncthreads();

        const int kq = lane >> 4;
        const int rr = lane & 15;
        bf16x8 af[2], bfr[8];
        #pragma unroll
        for (int mi = 0; mi < 2; ++mi)
            af[mi] = *(const bf16x8*)&A_s[(wv * 32 + mi * 16 + rr) * 40 + kq * 8];
        #pragma unroll
        for (int ni = 0; ni < 8; ++ni)
            bfr[ni] = *(const bf16x8*)&B_s[(ni * 16 + rr) * 40 + kq * 8];
        #pragma unroll
        for (int ni = 0; ni < 8; ++ni)
            #pragma unroll
            for (int mi = 0; mi < 2; ++mi)
                acc[mi][ni] = __builtin_amdgcn_mfma_f32_16x16x32_bf16(
                    af[mi], bfr[ni], acc[mi][ni], 0, 0, 0);
        __syncthreads();
    }

    const int rowbase = m_tile * 128 + wv * 32;
    const int cgrp = lane >> 4;
    const int cc   = lane & 15;
    #pragma unroll
    for (int ni = 0; ni < 8; ++ni) {
        int colp = nt * 128 + ni * 16 + cc;
        float bb = f_b[colp];
        #pragma unroll
        for (int mi = 0; mi < 2; ++mi) {
            #pragma unroll
            for (int i = 0; i < 4; ++i) {
                int row = rowbase + mi * 16 + cgrp * 4 + i;
                Fout[(long)row * 256 + colp] = f2bf(fast_tanh(acc[mi][ni][i] + bb));
            }
        }
    }
}

// ---------------------------------------------------------------------------
// K4: predict = sigmoid(f . p_W + p_b). One wave per 64 consecutive rows.
// ---------------------------------------------------------------------------
__global__ __launch_bounds__(256) void k4_pred(
    const unsigned short* __restrict__ Fws,
    const float* __restrict__ p_W, const float* __restrict__ p_b,
    float* __restrict__ out)
{
    const int tid  = threadIdx.x;
    const int lane = tid & 63;
    const int wgid = blockIdx.x * 4 + (tid >> 6);   // 0..2047
    const float4 pw = *(const float4*)(p_W + lane * 4);
    const float pb = p_b[0];
    #pragma unroll 4
    for (int r = 0; r < 64; ++r) {
        long row = (long)wgid * 64 + r;
        ushort4 q = *(const ushort4*)(Fws + row * 256 + lane * 4);
        float partial = bf2f(q.x) * pw.x + bf2f(q.y) * pw.y
                      + bf2f(q.z) * pw.z + bf2f(q.w) * pw.w;
        #pragma unroll
        for (int off = 32; off >= 1; off >>= 1) partial += __shfl_xor(partial, off);
        if (lane == 0) out[row] = fast_sigmoid(partial + pb);
    }
}

// ---------------------------------------------------------------------------
extern "C" void kernel_launch(void* const* d_in, const int* in_sizes, int n_in,
                              void* d_out, int out_size, void* d_ws, size_t ws_size,
                              hipStream_t stream)
{
    const int*   item_seq    = (const int*)d_in[0];
    const int*   correct_seq = (const int*)d_in[1];
    const float* k_emb = (const float*)d_in[2];
    const float* v_emb = (const float*)d_in[3];
    const float* Mk    = (const float*)d_in[4];
    const float* Mv0   = (const float*)d_in[5];
    const float* e_W   = (const float*)d_in[6];
    const float* e_b   = (const float*)d_in[7];
    const float* a_W   = (const float*)d_in[8];
    const float* a_b   = (const float*)d_in[9];
    const float* f_W   = (const float*)d_in[10];
    const float* f_b   = (const float*)d_in[11];
    const float* p_W   = (const float*)d_in[12];
    const float* p_b   = (const float*)d_in[13];
    float* out = (float*)d_out;

    // ws layout (bytes):
    //   [0,   32M)  Wws  w f16 [BT][128]      (k3 tables re-use this after k2)
    //   [32M, 96M)  Ews  e f16 [BT][256]      (aliased by f bf16 = k3 output)
    //   [96M, 160M) Aws  a f16 [BT][256]
    //   [160M,224M) Rws  reads bf16 [BT][256] (k1 bf16 tables live here pre-k2)
    char* ws = (char*)d_ws;
    unsigned short* Wws = (unsigned short*)(ws);
    unsigned short* Ews = (unsigned short*)(ws + 33554432ll);
    unsigned short* Aws = (unsigned short*)(ws + 100663296ll);
    unsigned short* Rws = (unsigned short*)(ws + 167772160ll);

    // k1-phase bf16 tables, parked in the (still dead) Rws region
    unsigned short* kA_bf = Rws;                 // 512000
    unsigned short* v_bf  = Rws + 512000;        // 1024000
    unsigned short* Mk_bf = Rws + 1536000;       // 32768
    unsigned short* eW_bf = Rws + 1568768;       // 65536
    unsigned short* aW_bf = Rws + 1634304;       // 65536
    // k3-phase bf16 tables, parked in the (dead after k2) Wws region
    unsigned short* k3_bf = Wws;                 // 512000
    unsigned short* fW_bf = Wws + 512000;        // 131072

    k0_cvt<<<dim3(1000, 5), dim3(256), 0, stream>>>(
        k_emb, v_emb, Mk, e_W, a_W,
        kA_bf, v_bf, Mk_bf, eW_bf, aW_bf,
        512000, 1024000, 32768, 65536, 65536);

    k1_wea<<<dim3(1024, 5), dim3(256), 0, stream>>>(
        item_seq, correct_seq, kA_bf, v_bf, Mk_bf, eW_bf, e_b, aW_bf, a_b,
        Wws, Ews, Aws);

    k2_scan<<<dim3(256), dim3(512), 0, stream>>>(Mv0, Wws, Ews, Aws, Rws);

    k0_cvt<<<dim3(500, 2), dim3(256), 0, stream>>>(
        k_emb, f_W, nullptr, nullptr, nullptr,
        k3_bf, fW_bf, nullptr, nullptr, nullptr,
        512000, 131072, 0, 0, 0);

    k3_f<<<dim3(1024, 2), dim3(256), 0, stream>>>(
        item_seq, k3_bf, fW_bf, f_b, Rws, Ews /* f overwrites e */);

    k4_pred<<<dim3(512), dim3(256), 0, stream>>>(Ews, p_W, p_b, out);
}

// Round 8
// 460.795 us; speedup vs baseline: 1.2534x; 1.0494x over previous
//
#include <hip/hip_runtime.h>
#include <hip/hip_bf16.h>
#include <hip/hip_fp16.h>

// DKVMN fused pipeline for MI355X (gfx950)
// B=256, T=512, DIM_KEY=256, DIM_VALUE=128, NUM_ITEM=2000
// k0_cvt : f32 tables -> bf16 tables in ws (MFMA operands)
// k1_wea : gather + [Mk|e_W|a_W] GEMM (bf16 MFMA); outputs w (f16 [pos][128])
//          and EA (f16 interleaved [pos][k][{-e, a}])
// k2_scan: scan with M in MFMA B-fragment layout. Read = w^T M offloaded to
//          the (idle) matrix pipe via mfma_f32_16x16x32_f16, v-sum inside the
//          MFMA accumulate chain -> NO LDS / barriers / readlane. VALU does
//          only the update: M = fma8(w8, fma8(-e8, M, a8), M). Dist-2 prefetch.
//          (R7 lesson: VOP3P packed = half-rate, VALU pinned ~213us -> use
//          the other pipe.)
// k3_f   : [reads|k] @ f_W^T GEMM + tanh, FUSED predict-dot epilogue -> pd
// k4_pred: out = sigmoid(pd[0]+pd[1]+p_b)  (1 MB instead of 64 MB f traffic)

#define T_SEQ 512
#define DK    256
#define DV    128
#define NITEM 2000
#define BT    131072   // 256*512

typedef __attribute__((ext_vector_type(8))) short bf16x8;
typedef __attribute__((ext_vector_type(4))) float f32x4;
typedef _Float16 f16x8 __attribute__((ext_vector_type(8)));

__device__ __forceinline__ float bf2f(unsigned short u) {
    return __uint_as_float(((unsigned int)u) << 16);
}
__device__ __forceinline__ unsigned short f2bf(float x) {   // RNE f32->bf16
    unsigned int u = __float_as_uint(x);
    return (unsigned short)((u + 0x7fffu + ((u >> 16) & 1u)) >> 16);
}
__device__ __forceinline__ unsigned short f2h(float x) {    // f32->f16
    _Float16 h = (_Float16)x;
    return __builtin_bit_cast(unsigned short, h);
}
__device__ __forceinline__ float fast_rcp(float x) { return __builtin_amdgcn_rcpf(x); }
__device__ __forceinline__ float fast_sigmoid(float x) { return fast_rcp(1.f + __expf(-x)); }
__device__ __forceinline__ float fast_tanh(float x) {
    float t = __expf(2.f * x);
    return (t - 1.f) * fast_rcp(t + 1.f);
}
__device__ __forceinline__ f16x8 fma8(f16x8 a, f16x8 b, f16x8 c) {
    return __builtin_elementwise_fma(a, b, c);
}
__device__ __forceinline__ f16x8 splat8(_Float16 x) {
    return (f16x8){x, x, x, x, x, x, x, x};
}
__device__ __forceinline__ _Float16 lo16(unsigned int u) {
    return __builtin_bit_cast(_Float16, (unsigned short)(u & 0xffffu));
}
__device__ __forceinline__ _Float16 hi16(unsigned int u) {
    return __builtin_bit_cast(_Float16, (unsigned short)(u >> 16));
}

// ---------------------------------------------------------------------------
// k0: f32 -> bf16 table conversion (up to 5 tables per launch, y = table id)
// ---------------------------------------------------------------------------
__global__ __launch_bounds__(256) void k0_cvt(
    const float* __restrict__ s0, const float* __restrict__ s1,
    const float* __restrict__ s2, const float* __restrict__ s3,
    const float* __restrict__ s4,
    unsigned short* __restrict__ d0, unsigned short* __restrict__ d1,
    unsigned short* __restrict__ d2, unsigned short* __restrict__ d3,
    unsigned short* __restrict__ d4,
    int n0, int n1, int n2, int n3, int n4)
{
    const float* s; unsigned short* d; int n;
    switch (blockIdx.y) {
        case 0:  s = s0; d = d0; n = n0; break;
        case 1:  s = s1; d = d1; n = n1; break;
        case 2:  s = s2; d = d2; n = n2; break;
        case 3:  s = s3; d = d3; n = n3; break;
        default: s = s4; d = d4; n = n4; break;
    }
    int i4 = (blockIdx.x * 256 + threadIdx.x) * 4;
    if (i4 < n) {
        float4 v = *(const float4*)(s + i4);
        ushort4 o;
        o.x = f2bf(v.x); o.y = f2bf(v.y); o.z = f2bf(v.z); o.w = f2bf(v.w);
        *(ushort4*)(d + i4) = o;
    }
}

// ---------------------------------------------------------------------------
// K1: 128 rows x 128 cols per block, 4 waves stacked by rows.
// n_tile 0 -> w (softmax, f16 [row][128]); 1,2 -> e halves (writes -sigmoid
// into EA even slots); 3,4 -> a halves (tanh into EA odd slots).
// ---------------------------------------------------------------------------
__global__ __launch_bounds__(256) void k1_wea(
    const int* __restrict__ item_seq, const int* __restrict__ correct_seq,
    const unsigned short* __restrict__ k_bf, const unsigned short* __restrict__ v_bf,
    const unsigned short* __restrict__ Mk_bf,
    const unsigned short* __restrict__ eW_bf, const float* __restrict__ e_b,
    const unsigned short* __restrict__ aW_bf, const float* __restrict__ a_b,
    unsigned short* __restrict__ Wout, unsigned short* __restrict__ EAout)
{
    const int m_tile = blockIdx.x;   // 0..1023
    const int n_tile = blockIdx.y;   // 0..4
    const int tid  = threadIdx.x;
    const int lane = tid & 63;
    const int wv   = tid >> 6;

    __shared__ int idx_s[128];
    __shared__ unsigned short A_s[128 * 40];
    __shared__ unsigned short B_s[128 * 40];

    const unsigned short* Atab = (n_tile == 0) ? k_bf : v_bf;
    const unsigned short* Wtab; int wrow0;
    if (n_tile == 0)      { Wtab = Mk_bf; wrow0 = 0;   }
    else if (n_tile == 1) { Wtab = eW_bf; wrow0 = 0;   }
    else if (n_tile == 2) { Wtab = eW_bf; wrow0 = 128; }
    else if (n_tile == 3) { Wtab = aW_bf; wrow0 = 0;   }
    else                  { Wtab = aW_bf; wrow0 = 128; }

    if (tid < 128) {
        int pos = m_tile * 128 + tid;
        int it = item_seq[pos];
        int co = correct_seq[pos];
        idx_s[tid] = (n_tile == 0) ? it : (it + NITEM * co);
    }
    __syncthreads();

    int myrow[4], myc4[4], myidx[4];
    #pragma unroll
    for (int j = 0; j < 4; ++j) {
        int chunk = tid + 256 * j;
        myrow[j] = chunk >> 3;
        myc4[j]  = chunk & 7;
        myidx[j] = idx_s[myrow[j]];
    }

    f32x4 acc[2][8];
    #pragma unroll
    for (int mi = 0; mi < 2; ++mi)
        #pragma unroll
        for (int ni = 0; ni < 8; ++ni)
            acc[mi][ni] = (f32x4){0.f, 0.f, 0.f, 0.f};

    for (int bk = 0; bk < 8; ++bk) {
        int k0 = bk * 32;
        #pragma unroll
        for (int j = 0; j < 4; ++j) {
            int row = myrow[j], c4 = myc4[j];
            *(ushort4*)&A_s[row * 40 + c4 * 4] =
                *(const ushort4*)(Atab + (long)myidx[j] * DK + k0 + c4 * 4);
            *(ushort4*)&B_s[row * 40 + c4 * 4] =
                *(const ushort4*)(Wtab + (long)(wrow0 + row) * DK + k0 + c4 * 4);
        }
        __syncthreads();

        const int kq = lane >> 4;   // k-slot 0..3 (8 bf16 each)
        const int rr = lane & 15;
        bf16x8 af[2], bfr[8];
        #pragma unroll
        for (int mi = 0; mi < 2; ++mi)
            af[mi] = *(const bf16x8*)&A_s[(wv * 32 + mi * 16 + rr) * 40 + kq * 8];
        #pragma unroll
        for (int ni = 0; ni < 8; ++ni)
            bfr[ni] = *(const bf16x8*)&B_s[(ni * 16 + rr) * 40 + kq * 8];
        #pragma unroll
        for (int ni = 0; ni < 8; ++ni)
            #pragma unroll
            for (int mi = 0; mi < 2; ++mi)
                acc[mi][ni] = __builtin_amdgcn_mfma_f32_16x16x32_bf16(
                    af[mi], bfr[ni], acc[mi][ni], 0, 0, 0);
        __syncthreads();
    }

    // C/D layout: col = lane&15, row = (lane>>4)*4 + reg (m89-verified)
    const int rowbase = m_tile * 128 + wv * 32;
    const int cgrp = lane >> 4;
    const int cc   = lane & 15;

    if (n_tile == 0) {
        #pragma unroll
        for (int mi = 0; mi < 2; ++mi) {
            #pragma unroll
            for (int i = 0; i < 4; ++i) {
                float m = -1e30f;
                #pragma unroll
                for (int ni = 0; ni < 8; ++ni) m = fmaxf(m, acc[mi][ni][i]);
                m = fmaxf(m, __shfl_xor(m, 1));
                m = fmaxf(m, __shfl_xor(m, 2));
                m = fmaxf(m, __shfl_xor(m, 4));
                m = fmaxf(m, __shfl_xor(m, 8));
                float p[8]; float s = 0.f;
                #pragma unroll
                for (int ni = 0; ni < 8; ++ni) { p[ni] = __expf(acc[mi][ni][i] - m); s += p[ni]; }
                s += __shfl_xor(s, 1); s += __shfl_xor(s, 2);
                s += __shfl_xor(s, 4); s += __shfl_xor(s, 8);
                float inv = fast_rcp(s);
                int row = rowbase + mi * 16 + cgrp * 4 + i;
                #pragma unroll
                for (int ni = 0; ni < 8; ++ni)
                    Wout[(long)row * 128 + ni * 16 + cc] = f2h(p[ni] * inv);
            }
        }
    } else {
        const bool is_e = (n_tile <= 2);
        const float* bias = is_e ? e_b : a_b;
        const int colbase = (is_e ? (n_tile - 1) : (n_tile - 3)) * 128;
        const int sel = is_e ? 0 : 1;
        #pragma unroll
        for (int ni = 0; ni < 8; ++ni) {
            int colp = colbase + ni * 16 + cc;
            float bb = bias[colp];
            #pragma unroll
            for (int mi = 0; mi < 2; ++mi) {
                #pragma unroll
                for (int i = 0; i < 4; ++i) {
                    int row = rowbase + mi * 16 + cgrp * 4 + i;
                    float x = acc[mi][ni][i] + bb;
                    float v = is_e ? -fast_sigmoid(x) : fast_tanh(x);  // e stored negated
                    EAout[(long)row * 512 + 2 * colp + sel] = f2h(v);
                }
            }
        }
    }
}

// ---------------------------------------------------------------------------
// K2: scan, MFMA-offloaded reads. 512 blocks = (batch, k-half), 256 thr =
// 4 waves, 0 LDS, 0 barriers. Wave owns all 128 v x 32 k (kw = kh*128+wv*32).
// M in B-fragment layout of mfma_f32_16x16x32_f16:
//   Mb[vt][kt][j] = M[v = vt*32 + (lane>>4)*8 + j][k = kw + kt*16 + (lane&15)]
// Per step: load w-frags (dwordx4, doubles as A-operand AND packed update
// multiplier), 1 EA dword per kt; 8 accumulating MFMAs compute read (pre-
// update values, D only stored -> off critical path); VALU update =
// 2 fma8 per (vt,kt). Dist-2 prefetch, named sets (R5: no big arrays).
// ---------------------------------------------------------------------------
__global__ __launch_bounds__(256, 4) void k2_scan(
    const float* __restrict__ Mv0,
    const unsigned short* __restrict__ Wws,
    const unsigned int* __restrict__ EAws,
    unsigned short* __restrict__ Rws)
{
    const int b    = blockIdx.x >> 1;
    const int kh   = blockIdx.x & 1;
    const int tid  = threadIdx.x;
    const int lane = tid & 63;
    const int wv   = tid >> 6;          // 0..3
    const int row16 = lane & 15;
    const int oct   = lane >> 4;        // v-octet within each 32-v tile
    const int kw    = kh * 128 + wv * 32;

    // M fragments (one-time f32 gather, coalesced 64B per (vt,kt,j) row)
    f16x8 Mb[4][2];
    #pragma unroll
    for (int vt = 0; vt < 4; ++vt)
        #pragma unroll
        for (int kt = 0; kt < 2; ++kt) {
            f16x8 m;
            #pragma unroll
            for (int j = 0; j < 8; ++j)
                m[j] = (_Float16)Mv0[(vt * 32 + oct * 8 + j) * DK + kw + kt * 16 + row16];
            Mb[vt][kt] = m;
        }

    const long pos0 = (long)b * T_SEQ;

    // dist-2 prefetch sets (w-frags as uint4[4]; EA dwords per kt)
    uint4 wfA[4], wfB[4];
    unsigned int eaA0, eaA1, eaB0, eaB1;
    {
        const unsigned short* wq = Wws + pos0 * 128 + oct * 8;
        wfA[0] = *(const uint4*)(wq);      wfA[1] = *(const uint4*)(wq + 32);
        wfA[2] = *(const uint4*)(wq + 64); wfA[3] = *(const uint4*)(wq + 96);
        wq += 128;
        wfB[0] = *(const uint4*)(wq);      wfB[1] = *(const uint4*)(wq + 32);
        wfB[2] = *(const uint4*)(wq + 64); wfB[3] = *(const uint4*)(wq + 96);
        eaA0 = EAws[pos0 * 256 + kw + row16];
        eaA1 = EAws[pos0 * 256 + kw + 16 + row16];
        eaB0 = EAws[(pos0 + 1) * 256 + kw + row16];
        eaB1 = EAws[(pos0 + 1) * 256 + kw + 16 + row16];
    }

#define K2_STEP(T, WF, EA0, EA1)                                               \
    {                                                                          \
        const uint4 w0 = WF[0], w1 = WF[1], w2 = WF[2], w3 = WF[3];            \
        const unsigned int ea0 = EA0, ea1 = EA1;                               \
        {   /* issue t+2 loads */                                              \
            long pn = pos0 + ((T) + 2 < T_SEQ ? (T) + 2 : T_SEQ - 1);          \
            const unsigned short* wq = Wws + pn * 128 + oct * 8;               \
            WF[0] = *(const uint4*)(wq);                                       \
            WF[1] = *(const uint4*)(wq + 32);                                  \
            WF[2] = *(const uint4*)(wq + 64);                                  \
            WF[3] = *(const uint4*)(wq + 96);                                  \
            EA0 = EAws[pn * 256 + kw + row16];                                 \
            EA1 = EAws[pn * 256 + kw + 16 + row16];                           \
        }                                                                      \
        const f16x8 w80 = __builtin_bit_cast(f16x8, w0);                       \
        const f16x8 w81 = __builtin_bit_cast(f16x8, w1);                       \
        const f16x8 w82 = __builtin_bit_cast(f16x8, w2);                       \
        const f16x8 w83 = __builtin_bit_cast(f16x8, w3);                       \
        /* reads on the matrix pipe, pre-update M (D not consumed by loop) */  \
        f32x4 D0 = (f32x4){0.f, 0.f, 0.f, 0.f};                                \
        f32x4 D1 = (f32x4){0.f, 0.f, 0.f, 0.f};                                \
        D0 = __builtin_amdgcn_mfma_f32_16x16x32_f16(w80, Mb[0][0], D0, 0,0,0); \
        D0 = __builtin_amdgcn_mfma_f32_16x16x32_f16(w81, Mb[1][0], D0, 0,0,0); \
        D0 = __builtin_amdgcn_mfma_f32_16x16x32_f16(w82, Mb[2][0], D0, 0,0,0); \
        D0 = __builtin_amdgcn_mfma_f32_16x16x32_f16(w83, Mb[3][0], D0, 0,0,0); \
        D1 = __builtin_amdgcn_mfma_f32_16x16x32_f16(w80, Mb[0][1], D1, 0,0,0); \
        D1 = __builtin_amdgcn_mfma_f32_16x16x32_f16(w81, Mb[1][1], D1, 0,0,0); \
        D1 = __builtin_amdgcn_mfma_f32_16x16x32_f16(w82, Mb[2][1], D1, 0,0,0); \
        D1 = __builtin_amdgcn_mfma_f32_16x16x32_f16(w83, Mb[3][1], D1, 0,0,0); \
        /* VALU update: M = M + w*(a - e*M); EA holds {-e, a} */               \
        const f16x8 ne80 = splat8(lo16(ea0)), a80 = splat8(hi16(ea0));         \
        const f16x8 ne81 = splat8(lo16(ea1)), a81 = splat8(hi16(ea1));         \
        Mb[0][0] = fma8(w80, fma8(ne80, Mb[0][0], a80), Mb[0][0]);             \
        Mb[1][0] = fma8(w81, fma8(ne80, Mb[1][0], a80), Mb[1][0]);             \
        Mb[2][0] = fma8(w82, fma8(ne80, Mb[2][0], a80), Mb[2][0]);             \
        Mb[3][0] = fma8(w83, fma8(ne80, Mb[3][0], a80), Mb[3][0]);             \
        Mb[0][1] = fma8(w80, fma8(ne81, Mb[0][1], a81), Mb[0][1]);             \
        Mb[1][1] = fma8(w81, fma8(ne81, Mb[1][1], a81), Mb[1][1]);             \
        Mb[2][1] = fma8(w82, fma8(ne81, Mb[2][1], a81), Mb[2][1]);             \
        Mb[3][1] = fma8(w83, fma8(ne81, Mb[3][1], a81), Mb[3][1]);             \
        /* store reads: all D rows identical (A rows = w for every row) */     \
        if (lane < 16) {                                                       \
            unsigned short* rp = Rws + (pos0 + (T)) * 256 + kw + lane;         \
            rp[0]  = f2bf(D0[0]);                                              \
            rp[16] = f2bf(D1[0]);                                              \
        }                                                                      \
    }

    for (int t = 0; t < T_SEQ; t += 2) {
        K2_STEP(t,     wfA, eaA0, eaA1)
        K2_STEP(t + 1, wfB, eaB0, eaB1)
    }
#undef K2_STEP
}

// ---------------------------------------------------------------------------
// K3: f = tanh([reads | k] @ f_W^T + f_b), fused predict-dot epilogue:
// writes pd[nt][row] = sum_{cols in tile} f * p_W  (f itself never stored).
// ---------------------------------------------------------------------------
__global__ __launch_bounds__(256) void k3_f(
    const int* __restrict__ item_seq,
    const unsigned short* __restrict__ k_bf,
    const unsigned short* __restrict__ fW_bf, const float* __restrict__ f_b,
    const float* __restrict__ p_W,
    const unsigned short* __restrict__ Rws,
    float* __restrict__ pd)
{
    const int m_tile = blockIdx.x;   // 0..1023
    const int nt  = blockIdx.y;      // 0..1
    const int tid = threadIdx.x;
    const int lane = tid & 63;
    const int wv   = tid >> 6;

    __shared__ int idx_s[128];
    __shared__ unsigned short A_s[128 * 40];
    __shared__ unsigned short B_s[128 * 40];

    if (tid < 128) idx_s[tid] = item_seq[m_tile * 128 + tid];
    __syncthreads();

    int myrow[4], myc4[4], myidx[4];
    #pragma unroll
    for (int j = 0; j < 4; ++j) {
        int chunk = tid + 256 * j;
        myrow[j] = chunk >> 3;
        myc4[j]  = chunk & 7;
        myidx[j] = idx_s[myrow[j]];
    }

    f32x4 acc[2][8];
    #pragma unroll
    for (int mi = 0; mi < 2; ++mi)
        #pragma unroll
        for (int ni = 0; ni < 8; ++ni)
            acc[mi][ni] = (f32x4){0.f, 0.f, 0.f, 0.f};

    for (int bk = 0; bk < 16; ++bk) {
        int k0 = bk * 32;
        #pragma unroll
        for (int j = 0; j < 4; ++j) {
            int row = myrow[j], c4 = myc4[j];
            ushort4 ap;
            if (k0 < 256) {
                long pos = (long)m_tile * 128 + row;
                ap = *(const ushort4*)(Rws + pos * 256 + k0 + c4 * 4);
            } else {
                ap = *(const ushort4*)(k_bf + (long)myidx[j] * DK + (k0 - 256) + c4 * 4);
            }
            *(ushort4*)&A_s[row * 40 + c4 * 4] = ap;
            *(ushort4*)&B_s[row * 40 + c4 * 4] =
                *(const ushort4*)(fW_bf + (long)(nt * 128 + row) * 512 + k0 + c4 * 4);
        }
        __syncthreads();

        const int kq = lane >> 4;
        const int rr = lane & 15;
        bf16x8 af[2], bfr[8];
        #pragma unroll
        for (int mi = 0; mi < 2; ++mi)
            af[mi] = *(const bf16x8*)&A_s[(wv * 32 + mi * 16 + rr) * 40 + kq * 8];
        #pragma unroll
        for (int ni = 0; ni < 8; ++ni)
            bfr[ni] = *(const bf16x8*)&B_s[(ni * 16 + rr) * 40 + kq * 8];
        #pragma unroll
        for (int ni = 0; ni < 8; ++ni)
            #pragma unroll
            for (int mi = 0; mi < 2; ++mi)
                acc[mi][ni] = __builtin_amdgcn_mfma_f32_16x16x32_bf16(
                    af[mi], bfr[ni], acc[mi][ni], 0, 0, 0);
        __syncthreads();
    }

    const int rowbase = m_tile * 128 + wv * 32;
    const int cgrp = lane >> 4;
    const int cc   = lane & 15;

    float pw[8];
    #pragma unroll
    for (int ni = 0; ni < 8; ++ni) pw[ni] = p_W[nt * 128 + ni * 16 + cc];

    float s[2][4] = {{0.f,0.f,0.f,0.f},{0.f,0.f,0.f,0.f}};
    #pragma unroll
    for (int ni = 0; ni < 8; ++ni) {
        float bb = f_b[nt * 128 + ni * 16 + cc];
        #pragma unroll
        for (int mi = 0; mi < 2; ++mi)
            #pragma unroll
            for (int i = 0; i < 4; ++i)
                s[mi][i] += fast_tanh(acc[mi][ni][i] + bb) * pw[ni];
    }
    // reduce across the 16-lane col group
    #pragma unroll
    for (int mi = 0; mi < 2; ++mi)
        #pragma unroll
        for (int i = 0; i < 4; ++i) {
            float v = s[mi][i];
            v += __shfl_xor(v, 1); v += __shfl_xor(v, 2);
            v += __shfl_xor(v, 4); v += __shfl_xor(v, 8);
            s[mi][i] = v;
        }
    if (cc == 0) {
        #pragma unroll
        for (int mi = 0; mi < 2; ++mi)
            #pragma unroll
            for (int i = 0; i < 4; ++i)
                pd[(long)nt * BT + rowbase + mi * 16 + cgrp * 4 + i] = s[mi][i];
    }
}

// ---------------------------------------------------------------------------
// K4: out = sigmoid(pd[0][row] + pd[1][row] + p_b)
// ---------------------------------------------------------------------------
__global__ __launch_bounds__(256) void k4_pred(
    const float* __restrict__ pd, const float* __restrict__ p_b,
    float* __restrict__ out)
{
    int i = blockIdx.x * 256 + threadIdx.x;
    out[i] = fast_sigmoid(pd[i] + pd[BT + i] + p_b[0]);
}

// ---------------------------------------------------------------------------
extern "C" void kernel_launch(void* const* d_in, const int* in_sizes, int n_in,
                              void* d_out, int out_size, void* d_ws, size_t ws_size,
                              hipStream_t stream)
{
    const int*   item_seq    = (const int*)d_in[0];
    const int*   correct_seq = (const int*)d_in[1];
    const float* k_emb = (const float*)d_in[2];
    const float* v_emb = (const float*)d_in[3];
    const float* Mk    = (const float*)d_in[4];
    const float* Mv0   = (const float*)d_in[5];
    const float* e_W   = (const float*)d_in[6];
    const float* e_b   = (const float*)d_in[7];
    const float* a_W   = (const float*)d_in[8];
    const float* a_b   = (const float*)d_in[9];
    const float* f_W   = (const float*)d_in[10];
    const float* f_b   = (const float*)d_in[11];
    const float* p_W   = (const float*)d_in[12];
    const float* p_b   = (const float*)d_in[13];
    float* out = (float*)d_out;

    // ws layout (bytes):
    //   [0,   32M)  Wws  w f16 [BT][128]       (k3 tables re-use after k2)
    //   [32M, 160M) EA   f16 [BT][256][{-e,a}] (dead after k2; pd parked here)
    //   [160M,224M) Rws  reads bf16 [BT][256]  (k1 bf16 tables live here pre-k2)
    char* ws = (char*)d_ws;
    unsigned short* Wws = (unsigned short*)(ws);
    unsigned short* EAo = (unsigned short*)(ws + 33554432ll);
    unsigned int*   EAi = (unsigned int*)(ws + 33554432ll);
    unsigned short* Rws = (unsigned short*)(ws + 167772160ll);
    float*          pd  = (float*)(ws + 33554432ll);   // EA region, dead after k2

    // k1-phase bf16 tables, parked in the (still dead) Rws region
    unsigned short* kA_bf = Rws;                 // 512000
    unsigned short* v_bf  = Rws + 512000;        // 1024000
    unsigned short* Mk_bf = Rws + 1536000;       // 32768
    unsigned short* eW_bf = Rws + 1568768;       // 65536
    unsigned short* aW_bf = Rws + 1634304;       // 65536
    // k3-phase bf16 tables, parked in the (dead after k2) Wws region
    unsigned short* k3_bf = Wws;                 // 512000
    unsigned short* fW_bf = Wws + 512000;        // 131072

    k0_cvt<<<dim3(1000, 5), dim3(256), 0, stream>>>(
        k_emb, v_emb, Mk, e_W, a_W,
        kA_bf, v_bf, Mk_bf, eW_bf, aW_bf,
        512000, 1024000, 32768, 65536, 65536);

    k1_wea<<<dim3(1024, 5), dim3(256), 0, stream>>>(
        item_seq, correct_seq, kA_bf, v_bf, Mk_bf, eW_bf, e_b, aW_bf, a_b,
        Wws, EAo);

    k2_scan<<<dim3(512), dim3(256), 0, stream>>>(Mv0, Wws, EAi, Rws);

    k0_cvt<<<dim3(500, 2), dim3(256), 0, stream>>>(
        k_emb, f_W, nullptr, nullptr, nullptr,
        k3_bf, fW_bf, nullptr, nullptr, nullptr,
        512000, 131072, 0, 0, 0);

    k3_f<<<dim3(1024, 2), dim3(256), 0, stream>>>(
        item_seq, k3_bf, fW_bf, f_b, p_W, Rws, pd);

    k4_pred<<<dim3(512), dim3(256), 0, stream>>>(pd, p_b, out);
}